// Round 6
// baseline (399.821 us; speedup 1.0000x reference)
//
#include <hip/hip_runtime.h>
#include <math.h>

#define N_   128
#define S_   1024
#define D_   128
#define SD_  (S_ * D_)     // 131072

#define WSP_PLANE 49152    // 3*4*4*4*32*8  (one hi or lo W plane, elements)
#define MSP_PLANE 16384    // 4*4*4*32*8    (one hi or lo M plane, elements)
#define NREP 64            // fallback (atomic) replica count
#define SB   2             // s-values per k_scores block
#define GRID_SC (S_ / SB)  // 512
#define PSTRIDE ((N_ + 1) * N_)   // per-partial stride: 128x128 scores + 128 tk row

typedef __attribute__((ext_vector_type(8))) short bf16x8;
typedef __attribute__((ext_vector_type(4))) short bf16x4;
typedef __attribute__((ext_vector_type(4))) float f32x4;
#define MFMA16 __builtin_amdgcn_mfma_f32_16x16x32_bf16

// pe(s): row i = s>>5, col c = s&31; arg = pi*i*1000^(-(c&~1)/128); sin if c even
__device__ __forceinline__ float pe_scale(int s) {
    int i = s >> 5;
    int c = s & 31;
    double rexp = pow(1000.0, -(double)(c & ~1) / 128.0);
    double arg = M_PI * (double)i * rexp;
    return (float)((c & 1) ? cos(arg) : sin(arg));
}

__device__ __forceinline__ unsigned short bf16_rn(float f) {
    unsigned int u = __float_as_uint(f);
    u += 0x7fff + ((u >> 16) & 1);
    return (unsigned short)(u >> 16);
}
__device__ __forceinline__ float bf16_f(unsigned short h) {
    return __uint_as_float(((unsigned int)h) << 16);
}
__device__ __forceinline__ void split2(float f, unsigned short& h, unsigned short& l) {
    h = bf16_rn(f);
    l = bf16_rn(f - bf16_f(h));
}

// load 8 consecutive fp32, scale, split into hi/lo bf16x8 frags (used by k_out)
__device__ __forceinline__ void load_split8(const float* p, float scale,
                                            bf16x8& hi, bf16x8& lo) {
    float4 u0 = *(const float4*)(p);
    float4 u1 = *(const float4*)(p + 4);
    unsigned short h[8], l[8];
    split2(u0.x * scale, h[0], l[0]); split2(u0.y * scale, h[1], l[1]);
    split2(u0.z * scale, h[2], l[2]); split2(u0.w * scale, h[3], l[3]);
    split2(u1.x * scale, h[4], l[4]); split2(u1.y * scale, h[5], l[5]);
    split2(u1.z * scale, h[6], l[6]); split2(u1.w * scale, h[7], l[7]);
    hi = bf16x8{(short)h[0],(short)h[1],(short)h[2],(short)h[3],
                (short)h[4],(short)h[5],(short)h[6],(short)h[7]};
    lo = bf16x8{(short)l[0],(short)l[1],(short)l[2],(short)l[3],
                (short)l[4],(short)l[5],(short)l[6],(short)l[7]};
}

// ---------------------------------------------------------------------------
// K0: split W (fp32 [384][128]) into hi/lo bf16 planes in MFMA-frag-swizzled
// layout Wsp[h][p][rc][ks][quad][m(32)][j(8)]. Also fills pe table (1024 f32).
// grid 192 x 256. (Only p=2 of Wsp is consumed now, by k_out.)
// ---------------------------------------------------------------------------
__global__ __launch_bounds__(256) void k_prep(const float* __restrict__ W,
                                              unsigned short* __restrict__ Wsp,
                                              float* __restrict__ peT) {
    const int idx = blockIdx.x * 256 + threadIdx.x;  // 0..49151
    if (idx < S_) peT[idx] = pe_scale(idx);
    const int rg = idx >> 7;         // W row (feature f)
    const int d  = idx & 127;
    const int p  = rg % 3;
    const int r  = rg / 3;
    const int rc = r >> 5, m = r & 31;
    const int ks = d >> 5, quad = (d >> 3) & 3, j = d & 7;
    unsigned short h, l;
    split2(W[idx], h, l);
    const size_t off = (size_t)((((p * 4 + rc) * 4 + ks) * 4 + quad) * 32 + m) * 8 + j;
    Wsp[off] = h;
    Wsp[off + WSP_PLANE] = l;
}

// ---------------------------------------------------------------------------
// K0b: M = Wq^T Wk (fp32, M[dp][e] = sum_g W[3g][dp]*W[3g+1][e]) split into
// hi/lo planes in frag-swizzled layout Msp[rc][ks][quad][m(32)][j(8)], and
// u[e] = sum_g b[3g]*W[3g+1][e]. grid 128 x 128.
// ---------------------------------------------------------------------------
__global__ __launch_bounds__(128) void k_prepM(const float* __restrict__ W,
                                               const float* __restrict__ b,
                                               unsigned short* __restrict__ Msp,
                                               float* __restrict__ uo) {
    const int dp = blockIdx.x;      // output row d'
    const int e  = threadIdx.x;     // input col e
    float acc = 0.f;
#pragma unroll 4
    for (int g = 0; g < 128; ++g)
        acc += W[(3 * g) * 128 + dp] * W[(3 * g + 1) * 128 + e];
    unsigned short h, l;
    split2(acc, h, l);
    const int rc = dp >> 5, m = dp & 31;
    const int ks = e >> 5, quad = (e >> 3) & 3, j = e & 7;
    const size_t off = (size_t)(((rc * 4 + ks) * 4 + quad) * 32 + m) * 8 + j;
    Msp[off] = h;
    Msp[off + MSP_PLANE] = l;
    if (blockIdx.x == 0) {
        float ua = 0.f;
#pragma unroll 4
        for (int g = 0; g < 128; ++g)
            ua += b[3 * g] * W[(3 * g + 1) * 128 + e];
        uo[e] = ua;
    }
}

// ---------------------------------------------------------------------------
// K1: partial scores via the M-restructure:
//   scores[n,n'] = sum_s x[n,s]^T (ps^2 M) x[n',s]  + tk[n']   (row-constant
//   terms dropped: softmax-invariant).
// Per ss: one projection y = (ps^2 M) x (3-term split MFMA), y through
// ping-pong LDS (ONE barrier per rc), score A-operand = held raw-x frags.
// tk[n'] = sum_s ps*(u . x[n',s]) accumulated in fp32 during the x load,
// stored as row 128 of the partial. grid GRID_SC x 512.
// ---------------------------------------------------------------------------
__global__ __launch_bounds__(512, 4) void k_scores(const float* __restrict__ x,
                                                   const unsigned short* __restrict__ Msp,
                                                   const float* __restrict__ u,
                                                   const float* __restrict__ peT,
                                                   float* __restrict__ sc,
                                                   int store_mode) {
    __shared__ unsigned short y2[2][2][128 * 40];   // [buf][hi/lo] : [n][r]
    __shared__ float ul[128];

    const int t    = threadIdx.x;
    const int lane = t & 63;
    const int wv   = t >> 6;        // wave 0..7
    const int lid  = lane & 15;
    const int quad = lane >> 4;

    if (t < 128) ul[t] = u[t];
    __syncthreads();

    const f32x4 fzero = {0.f, 0.f, 0.f, 0.f};
    f32x4 sacc[8];
#pragma unroll
    for (int j = 0; j < 8; ++j) sacc[j] = fzero;
    float tk = 0.f;

    for (int ss = 0; ss < SB; ++ss) {
        const int s = blockIdx.x * SB + ss;
        const float ps = peT[s];
        const float ps2 = ps * ps;

        // ---- held RAW x frags (rows n=wv*16+lid, k=ks*32+quad*8) + u-dot ----
        bf16x8 xh[4], xl[4];
        {
            const int row = wv * 16 + lid;
            const float* xp = x + (size_t)row * SD_ + (size_t)s * D_;
            float dot = 0.f;
#pragma unroll
            for (int ks = 0; ks < 4; ++ks) {
                const float* pp = xp + ks * 32 + quad * 8;
                float4 u0 = *(const float4*)pp;
                float4 u1 = *(const float4*)(pp + 4);
                const float* uu = &ul[ks * 32 + quad * 8];
                dot += u0.x * uu[0] + u0.y * uu[1] + u0.z * uu[2] + u0.w * uu[3]
                     + u1.x * uu[4] + u1.y * uu[5] + u1.z * uu[6] + u1.w * uu[7];
                unsigned short h[8], l[8];
                split2(u0.x, h[0], l[0]); split2(u0.y, h[1], l[1]);
                split2(u0.z, h[2], l[2]); split2(u0.w, h[3], l[3]);
                split2(u1.x, h[4], l[4]); split2(u1.y, h[5], l[5]);
                split2(u1.z, h[6], l[6]); split2(u1.w, h[7], l[7]);
                xh[ks] = bf16x8{(short)h[0],(short)h[1],(short)h[2],(short)h[3],
                                (short)h[4],(short)h[5],(short)h[6],(short)h[7]};
                xl[ks] = bf16x8{(short)l[0],(short)l[1],(short)l[2],(short)l[3],
                                (short)l[4],(short)l[5],(short)l[6],(short)l[7]};
            }
            tk += ps * dot;
        }

#pragma unroll
        for (int rc = 0; rc < 4; ++rc) {
            const int buf = rc & 1;   // ping-pong (ss*4 is even)
            // ---- projection: y rows rc*32..+32 = M @ x (3-term split) ----
            f32x4 pacc[2];
            pacc[0] = fzero; pacc[1] = fzero;
#pragma unroll
            for (int ks = 0; ks < 4; ++ks) {
                const unsigned short* mb =
                    Msp + (size_t)((rc * 4 + ks) * 4 + quad) * 256;
                bf16x8 wh[2], wl[2];
#pragma unroll
                for (int mt = 0; mt < 2; ++mt) {
                    wh[mt] = *(const bf16x8*)(mb + (mt * 16 + lid) * 8);
                    wl[mt] = *(const bf16x8*)(mb + MSP_PLANE + (mt * 16 + lid) * 8);
                }
#pragma unroll
                for (int mt = 0; mt < 2; ++mt) {
                    pacc[mt] = MFMA16(wh[mt], xh[ks], pacc[mt], 0, 0, 0);
                    pacc[mt] = MFMA16(wh[mt], xl[ks], pacc[mt], 0, 0, 0);
                    pacc[mt] = MFMA16(wl[mt], xh[ks], pacc[mt], 0, 0, 0);
                }
            }
            // epilogue: *ps^2, split, write transposed into y2[buf][.][n][r]
#pragma unroll
            for (int mt = 0; mt < 2; ++mt) {
                const int n = wv * 16 + lid;
                unsigned short hh[4], ll[4];
#pragma unroll
                for (int r = 0; r < 4; ++r) {
                    float yv = pacc[mt][r] * ps2;
                    split2(yv, hh[r], ll[r]);
                }
                bf16x4 hv = {(short)hh[0], (short)hh[1], (short)hh[2], (short)hh[3]};
                bf16x4 lv = {(short)ll[0], (short)ll[1], (short)ll[2], (short)ll[3]};
                *(bf16x4*)&y2[buf][0][n * 40 + mt * 16 + quad * 4] = hv;
                *(bf16x4*)&y2[buf][1][n * 40 + mt * 16 + quad * 4] = lv;
            }
            __syncthreads();
            // ---- scores += x @ y^T over this 32-d chunk (A = held x frags) ----
#pragma unroll
            for (int ntp = 0; ntp < 8; ++ntp) {
                const int yrow = ntp * 16 + lid;
                bf16x8 yh = *(const bf16x8*)&y2[buf][0][yrow * 40 + quad * 8];
                bf16x8 yl = *(const bf16x8*)&y2[buf][1][yrow * 40 + quad * 8];
                sacc[ntp] = MFMA16(xh[rc], yh, sacc[ntp], 0, 0, 0);
                sacc[ntp] = MFMA16(xh[rc], yl, sacc[ntp], 0, 0, 0);
                sacc[ntp] = MFMA16(xl[rc], yh, sacc[ntp], 0, 0, 0);
            }
            // no trailing barrier: next rc writes the OTHER buffer; the
            // following iteration's barrier orders reuse of this one.
        }
    }

    // ---- tk: reduce across the 4 quads (each holds a 32-d slice) ----
    tk += __shfl_xor(tk, 16);
    tk += __shfl_xor(tk, 32);

    // ---- write partial (store mode) or atomic accumulate (fallback) ----
    float* rep = sc + (size_t)(store_mode ? blockIdx.x
                                          : (blockIdx.x & (NREP - 1))) * PSTRIDE;
    if (store_mode) {
#pragma unroll
        for (int ntp = 0; ntp < 8; ++ntp)
#pragma unroll
            for (int r = 0; r < 4; ++r) {
                const int n  = wv * 16 + quad * 4 + r;
                const int np = ntp * 16 + lid;
                rep[n * N_ + np] = sacc[ntp][r];
            }
        if (quad == 0) rep[N_ * N_ + wv * 16 + lid] = tk;
    } else {
#pragma unroll
        for (int ntp = 0; ntp < 8; ++ntp)
#pragma unroll
            for (int r = 0; r < 4; ++r) {
                const int n  = wv * 16 + quad * 4 + r;
                const int np = ntp * 16 + lid;
                atomicAdd(&rep[n * N_ + np], sacc[ntp][r]);
            }
        if (quad == 0) atomicAdd(&rep[N_ * N_ + wv * 16 + lid], tk);
    }
}

// ---------------------------------------------------------------------------
// K2: sum R partials (scores quad-term + tk row), add tk[n'], softmax, write
// attn pre-swizzled into B-frag layout att2[ks][quad][n][j]. grid 128 x 1024.
// ---------------------------------------------------------------------------
__global__ __launch_bounds__(1024) void k_softmax(const float* __restrict__ sc, int R,
                                                  unsigned short* __restrict__ att2) {
    const int n  = blockIdx.x;
    const int t  = threadIdx.x;          // 0..1023
    const int rg = t >> 5;               // 0..31: rep-group
    const int c4 = (t & 31) * 4;         // column quad

    float4 a  = {0.f, 0.f, 0.f, 0.f};
    float4 tk = {0.f, 0.f, 0.f, 0.f};
    for (int rep = rg; rep < R; rep += 32) {
        const size_t base = (size_t)rep * PSTRIDE;
        const float4 p = *(const float4*)&sc[base + n * N_ + c4];
        a.x += p.x; a.y += p.y; a.z += p.z; a.w += p.w;
        const float4 q = *(const float4*)&sc[base + N_ * N_ + c4];
        tk.x += q.x; tk.y += q.y; tk.z += q.z; tk.w += q.w;
    }
    __shared__ float tmp[32][128];
    __shared__ float tmp2[32][128];
    *(float4*)&tmp[rg][c4]  = a;
    *(float4*)&tmp2[rg][c4] = tk;
    __syncthreads();

    __shared__ float red[2];
    __shared__ float red2[2];

    float v = 0.f;
    if (t < 128) {
        float q = 0.f, k = 0.f;
#pragma unroll
        for (int g = 0; g < 32; ++g) { q += tmp[g][t]; k += tmp2[g][t]; }
        v = (q + k) * 0.08838834764831845f;   // 1/sqrt(128)
    }

    float m = v;
#pragma unroll
    for (int o = 32; o > 0; o >>= 1) m = fmaxf(m, __shfl_xor(m, o));
    if (t < 128 && (t & 63) == 0) red[t >> 6] = m;
    __syncthreads();
    m = fmaxf(red[0], red[1]);

    float e = (t < 128) ? expf(v - m) : 0.f;
    float sum = e;
#pragma unroll
    for (int o = 32; o > 0; o >>= 1) sum += __shfl_xor(sum, o);
    if (t < 128 && (t & 63) == 0) red2[t >> 6] = sum;
    __syncthreads();
    sum = red2[0] + red2[1];

    if (t < 128) {
        const int ks = t >> 5, quad = (t >> 3) & 3, j = t & 7;
        att2[(size_t)(((ks * 4 + quad) * 128) + n) * 8 + j] = bf16_rn(e / sum);
    }
}

// ---------------------------------------------------------------------------
// K3: out[n, s*128+r] = sum_n' attn[n,n'] * v_s[n',r]. grid 1024 x 256.
// LDS: vT only (~35KB). Wv from pre-split Wsp (p=2), attn from att2.
// ---------------------------------------------------------------------------
__global__ __launch_bounds__(256, 2) void k_out(const float* __restrict__ x,
                                                const unsigned short* __restrict__ Wsp,
                                                const float* __restrict__ b,
                                                const unsigned short* __restrict__ att2,
                                                const float* __restrict__ peT,
                                                float* __restrict__ out) {
    __shared__ unsigned short vT[128 * 136];     // [r][n'] bf16
    __shared__ float bv[128];

    const int t    = threadIdx.x;
    const int lane = t & 63;
    const int wv   = t >> 6;
    const int lid  = lane & 15;
    const int quad = lane >> 4;
    const int s    = blockIdx.x;
    const float ps = peT[s];

    if (t < 128) bv[t] = b[3 * t + 2];
    __syncthreads();

    const f32x4 fzero = {0.f, 0.f, 0.f, 0.f};

    // ---- held xs A-frags: rows n=(wv*2+mt)*16+lid ----
    bf16x8 xh[2][4], xl[2][4];
#pragma unroll
    for (int mt = 0; mt < 2; ++mt) {
        const int row = (wv * 2 + mt) * 16 + lid;
        const float* xp = x + (size_t)row * SD_ + (size_t)s * D_;
#pragma unroll
        for (int ks = 0; ks < 4; ++ks)
            load_split8(xp + ks * 32 + quad * 8, ps, xh[mt][ks], xl[mt][ks]);
    }

    // ---- v-proj: v = xs @ Wv^T (3-term split); vT chunks disjoint, no syncs ----
    for (int rc = 0; rc < 4; ++rc) {
        f32x4 vacc[2][2];
        vacc[0][0] = fzero; vacc[0][1] = fzero; vacc[1][0] = fzero; vacc[1][1] = fzero;
#pragma unroll
        for (int ks = 0; ks < 4; ++ks) {
            const unsigned short* wb =
                Wsp + (size_t)(((2 * 4 + rc) * 4 + ks) * 4 + quad) * 256;
            bf16x8 wh[2], wl[2];
#pragma unroll
            for (int nt = 0; nt < 2; ++nt) {
                wh[nt] = *(const bf16x8*)(wb + (nt * 16 + lid) * 8);
                wl[nt] = *(const bf16x8*)(wb + WSP_PLANE + (nt * 16 + lid) * 8);
            }
#pragma unroll
            for (int mt = 0; mt < 2; ++mt)
#pragma unroll
                for (int nt = 0; nt < 2; ++nt) {
                    vacc[mt][nt] = MFMA16(xh[mt][ks], wh[nt], vacc[mt][nt], 0, 0, 0);
                    vacc[mt][nt] = MFMA16(xh[mt][ks], wl[nt], vacc[mt][nt], 0, 0, 0);
                    vacc[mt][nt] = MFMA16(xl[mt][ks], wh[nt], vacc[mt][nt], 0, 0, 0);
                }
        }
#pragma unroll
        for (int mt = 0; mt < 2; ++mt)
#pragma unroll
            for (int nt = 0; nt < 2; ++nt) {
                const int r = rc * 32 + nt * 16 + lid;
                const float bias = bv[r];
                unsigned short hh[4];
#pragma unroll
                for (int i = 0; i < 4; ++i) hh[i] = bf16_rn(vacc[mt][nt][i] + bias);
                bf16x4 hv = {(short)hh[0], (short)hh[1], (short)hh[2], (short)hh[3]};
                *(bf16x4*)&vT[r * 136 + (wv * 2 + mt) * 16 + quad * 4] = hv;
            }
    }
    __syncthreads();

    // ---- PV: outT = vT @ attnT (plain bf16, attn B-frags from att2) ----
    {
        f32x4 oacc[2][8];
#pragma unroll
        for (int i = 0; i < 2; ++i)
#pragma unroll
            for (int j = 0; j < 8; ++j) oacc[i][j] = fzero;
#pragma unroll
        for (int ks = 0; ks < 4; ++ks) {
            const int kofs = ks * 32 + quad * 8;
            bf16x8 a[2];
#pragma unroll
            for (int mt = 0; mt < 2; ++mt)
                a[mt] = *(const bf16x8*)&vT[((wv * 2 + mt) * 16 + lid) * 136 + kofs];
#pragma unroll
            for (int nt = 0; nt < 8; ++nt) {
                bf16x8 bb = *(const bf16x8*)&att2[(size_t)(((ks * 4 + quad) * 128) +
                                                           (nt * 16 + lid)) * 8];
#pragma unroll
                for (int mt = 0; mt < 2; ++mt)
                    oacc[mt][nt] = MFMA16(a[mt], bb, oacc[mt][nt], 0, 0, 0);
            }
        }
#pragma unroll
        for (int mt = 0; mt < 2; ++mt)
#pragma unroll
            for (int nt = 0; nt < 8; ++nt) {
                const int r = (wv * 2 + mt) * 16 + quad * 4;
                const int n = nt * 16 + lid;
                *(float4*)&out[(size_t)n * SD_ + (size_t)s * D_ + r] = *(float4*)&oacc[mt][nt];
            }
    }
}

// ---------------------------------------------------------------------------
extern "C" void kernel_launch(void* const* d_in, const int* in_sizes, int n_in,
                              void* d_out, int out_size, void* d_ws, size_t ws_size,
                              hipStream_t stream) {
    const float* x = (const float*)d_in[0];
    const float* W = (const float*)d_in[1];
    const float* b = (const float*)d_in[2];
    float* out = (float*)d_out;

    const size_t store_bytes = (size_t)GRID_SC * PSTRIDE * sizeof(float);  // ~32.3 MiB
    const size_t rep_bytes   = (size_t)NREP * PSTRIDE * sizeof(float);     // ~4.2 MB
    const size_t tail_bytes  = (size_t)N_ * N_ * sizeof(unsigned short)        // att2
                             + (size_t)2 * WSP_PLANE * sizeof(unsigned short)  // Wsp
                             + (size_t)S_ * sizeof(float)                      // peT
                             + (size_t)2 * MSP_PLANE * sizeof(unsigned short)  // Msp
                             + (size_t)N_ * sizeof(float);                     // u
    const int store_mode = (ws_size >= store_bytes + tail_bytes) ? 1 : 0;
    const size_t sc_bytes = store_mode ? store_bytes : rep_bytes;

    // ws layout: scores region | att2 | Wsp | peT | Msp | u
    float* scores        = (float*)d_ws;
    unsigned short* att2 = (unsigned short*)((char*)d_ws + sc_bytes);
    unsigned short* Wsp  = att2 + N_ * N_;
    float* peT           = (float*)(Wsp + 2 * WSP_PLANE);
    unsigned short* Msp  = (unsigned short*)(peT + S_);
    float* uvec          = (float*)(Msp + 2 * MSP_PLANE);

    if (!store_mode)
        hipMemsetAsync(scores, 0, sc_bytes, stream);

    hipLaunchKernelGGL(k_prep,    dim3(192),     dim3(256),  0, stream, W, Wsp, peT);
    hipLaunchKernelGGL(k_prepM,   dim3(128),     dim3(128),  0, stream, W, b, Msp, uvec);
    hipLaunchKernelGGL(k_scores,  dim3(GRID_SC), dim3(512),  0, stream, x, Msp, uvec, peT,
                       scores, store_mode);
    hipLaunchKernelGGL(k_softmax, dim3(N_),      dim3(1024), 0, stream, scores,
                       store_mode ? GRID_SC : NREP, att2);
    hipLaunchKernelGGL(k_out,     dim3(1024),    dim3(256),  0, stream, x, Wsp, b, att2,
                       peT, out);
}

// Round 7
// 293.920 us; speedup vs baseline: 1.3603x; 1.3603x over previous
//
#include <hip/hip_runtime.h>
#include <math.h>

#define N_   128
#define S_   1024
#define D_   128
#define SD_  (S_ * D_)     // 131072

#define WSP_PLANE 49152    // 3*4*4*4*32*8  (one hi or lo W plane, elements)
#define MSP_PLANE 16384    // 4*4*4*32*8    (one hi or lo M plane, elements)
#define NREP 64            // fallback (atomic) replica count
#define SB   2             // s-values per k_scores block
#define GRID_SC (S_ / SB)  // 512
#define PSTRIDE ((N_ + 1) * N_)   // per-partial stride: 128x128 scores + 128 tk row

typedef __attribute__((ext_vector_type(8))) short bf16x8;
typedef __attribute__((ext_vector_type(4))) short bf16x4;
typedef __attribute__((ext_vector_type(4))) float f32x4;
#define MFMA16 __builtin_amdgcn_mfma_f32_16x16x32_bf16

// pe(s): row i = s>>5, col c = s&31; arg = pi*i*1000^(-(c&~1)/128); sin if c even
__device__ __forceinline__ float pe_scale(int s) {
    int i = s >> 5;
    int c = s & 31;
    double rexp = pow(1000.0, -(double)(c & ~1) / 128.0);
    double arg = M_PI * (double)i * rexp;
    return (float)((c & 1) ? cos(arg) : sin(arg));
}

__device__ __forceinline__ unsigned short bf16_rn(float f) {
    unsigned int u = __float_as_uint(f);
    u += 0x7fff + ((u >> 16) & 1);
    return (unsigned short)(u >> 16);
}
__device__ __forceinline__ float bf16_f(unsigned short h) {
    return __uint_as_float(((unsigned int)h) << 16);
}
__device__ __forceinline__ void split2(float f, unsigned short& h, unsigned short& l) {
    h = bf16_rn(f);
    l = bf16_rn(f - bf16_f(h));
}

// load 8 consecutive fp32, scale, split into hi/lo bf16x8 frags (used by k_out)
__device__ __forceinline__ void load_split8(const float* p, float scale,
                                            bf16x8& hi, bf16x8& lo) {
    float4 u0 = *(const float4*)(p);
    float4 u1 = *(const float4*)(p + 4);
    unsigned short h[8], l[8];
    split2(u0.x * scale, h[0], l[0]); split2(u0.y * scale, h[1], l[1]);
    split2(u0.z * scale, h[2], l[2]); split2(u0.w * scale, h[3], l[3]);
    split2(u1.x * scale, h[4], l[4]); split2(u1.y * scale, h[5], l[5]);
    split2(u1.z * scale, h[6], l[6]); split2(u1.w * scale, h[7], l[7]);
    hi = bf16x8{(short)h[0],(short)h[1],(short)h[2],(short)h[3],
                (short)h[4],(short)h[5],(short)h[6],(short)h[7]};
    lo = bf16x8{(short)l[0],(short)l[1],(short)l[2],(short)l[3],
                (short)l[4],(short)l[5],(short)l[6],(short)l[7]};
}

// ---------------------------------------------------------------------------
// K0: split W (fp32 [384][128]) into hi/lo bf16 planes in MFMA-frag-swizzled
// layout Wsp[h][p][rc][ks][quad][m(32)][j(8)]. Also fills pe table (1024 f32).
// grid 192 x 256. (Only p=2 of Wsp is consumed now, by k_out.)
// ---------------------------------------------------------------------------
__global__ __launch_bounds__(256) void k_prep(const float* __restrict__ W,
                                              unsigned short* __restrict__ Wsp,
                                              float* __restrict__ peT) {
    const int idx = blockIdx.x * 256 + threadIdx.x;  // 0..49151
    if (idx < S_) peT[idx] = pe_scale(idx);
    const int rg = idx >> 7;         // W row (feature f)
    const int d  = idx & 127;
    const int p  = rg % 3;
    const int r  = rg / 3;
    const int rc = r >> 5, m = r & 31;
    const int ks = d >> 5, quad = (d >> 3) & 3, j = d & 7;
    unsigned short h, l;
    split2(W[idx], h, l);
    const size_t off = (size_t)((((p * 4 + rc) * 4 + ks) * 4 + quad) * 32 + m) * 8 + j;
    Wsp[off] = h;
    Wsp[off + WSP_PLANE] = l;
}

// ---------------------------------------------------------------------------
// K0b: M = Wq^T Wk (fp32, M[dp][e] = sum_g W[3g][dp]*W[3g+1][e]) split into
// hi/lo planes in frag-swizzled layout Msp[rc][ks][quad][m(32)][j(8)], and
// u[e] = sum_g b[3g]*W[3g+1][e]. grid 128 x 128.
// ---------------------------------------------------------------------------
__global__ __launch_bounds__(128) void k_prepM(const float* __restrict__ W,
                                               const float* __restrict__ b,
                                               unsigned short* __restrict__ Msp,
                                               float* __restrict__ uo) {
    const int dp = blockIdx.x;      // output row d'
    const int e  = threadIdx.x;     // input col e
    float acc = 0.f;
#pragma unroll 4
    for (int g = 0; g < 128; ++g)
        acc += W[(3 * g) * 128 + dp] * W[(3 * g + 1) * 128 + e];
    unsigned short h, l;
    split2(acc, h, l);
    const int rc = dp >> 5, m = dp & 31;
    const int ks = e >> 5, quad = (e >> 3) & 3, j = e & 7;
    const size_t off = (size_t)(((rc * 4 + ks) * 4 + quad) * 32 + m) * 8 + j;
    Msp[off] = h;
    Msp[off + MSP_PLANE] = l;
    if (blockIdx.x == 0) {
        float ua = 0.f;
#pragma unroll 4
        for (int g = 0; g < 128; ++g)
            ua += b[3 * g] * W[(3 * g + 1) * 128 + e];
        uo[e] = ua;
    }
}

// ---------------------------------------------------------------------------
// K1: partial scores via the M-restructure:
//   scores[n,n'] = sum_s x[n,s]^T (ps^2 M) x[n',s]  + tk[n']   (row-constant
//   terms dropped: softmax-invariant).
// Per ss: one projection y = (ps^2 M) x (3-term split MFMA), y through
// ping-pong LDS (ONE barrier per rc), score A-operand = held raw-x frags.
// tk[n'] = sum_s ps*(u . x[n',s]) accumulated in fp32 during the x load,
// stored as row 128 of the partial. grid GRID_SC x 512.
// __launch_bounds__(512, 2): VGPR cap >=128 — peak live state is ~110 VGPRs
// (xh/xl 32 + sacc 32 + projection working set); the previous (512,4) bound
// capped allocation at 64 and spilled ~280 MB each way to scratch (R6).
// ---------------------------------------------------------------------------
__global__ __launch_bounds__(512, 2) void k_scores(const float* __restrict__ x,
                                                   const unsigned short* __restrict__ Msp,
                                                   const float* __restrict__ u,
                                                   const float* __restrict__ peT,
                                                   float* __restrict__ sc,
                                                   int store_mode) {
    __shared__ unsigned short y2[2][2][128 * 40];   // [buf][hi/lo] : [n][r]
    __shared__ float ul[128];

    const int t    = threadIdx.x;
    const int lane = t & 63;
    const int wv   = t >> 6;        // wave 0..7
    const int lid  = lane & 15;
    const int quad = lane >> 4;

    if (t < 128) ul[t] = u[t];
    __syncthreads();

    const f32x4 fzero = {0.f, 0.f, 0.f, 0.f};
    f32x4 sacc[8];
#pragma unroll
    for (int j = 0; j < 8; ++j) sacc[j] = fzero;
    float tk = 0.f;

    for (int ss = 0; ss < SB; ++ss) {
        const int s = blockIdx.x * SB + ss;
        const float ps = peT[s];
        const float ps2 = ps * ps;

        // ---- held RAW x frags (rows n=wv*16+lid, k=ks*32+quad*8) + u-dot ----
        bf16x8 xh[4], xl[4];
        {
            const int row = wv * 16 + lid;
            const float* xp = x + (size_t)row * SD_ + (size_t)s * D_;
            float dot = 0.f;
#pragma unroll
            for (int ks = 0; ks < 4; ++ks) {
                const float* pp = xp + ks * 32 + quad * 8;
                float4 u0 = *(const float4*)pp;
                float4 u1 = *(const float4*)(pp + 4);
                const float* uu = &ul[ks * 32 + quad * 8];
                dot += u0.x * uu[0] + u0.y * uu[1] + u0.z * uu[2] + u0.w * uu[3]
                     + u1.x * uu[4] + u1.y * uu[5] + u1.z * uu[6] + u1.w * uu[7];
                unsigned short h[8], l[8];
                split2(u0.x, h[0], l[0]); split2(u0.y, h[1], l[1]);
                split2(u0.z, h[2], l[2]); split2(u0.w, h[3], l[3]);
                split2(u1.x, h[4], l[4]); split2(u1.y, h[5], l[5]);
                split2(u1.z, h[6], l[6]); split2(u1.w, h[7], l[7]);
                xh[ks] = bf16x8{(short)h[0],(short)h[1],(short)h[2],(short)h[3],
                                (short)h[4],(short)h[5],(short)h[6],(short)h[7]};
                xl[ks] = bf16x8{(short)l[0],(short)l[1],(short)l[2],(short)l[3],
                                (short)l[4],(short)l[5],(short)l[6],(short)l[7]};
            }
            tk += ps * dot;
        }

#pragma unroll
        for (int rc = 0; rc < 4; ++rc) {
            const int buf = rc & 1;   // ping-pong (ss*4 is even)
            // ---- projection: y rows rc*32..+32 = M @ x (3-term split) ----
            f32x4 pacc[2];
            pacc[0] = fzero; pacc[1] = fzero;
#pragma unroll
            for (int ks = 0; ks < 4; ++ks) {
                const unsigned short* mb =
                    Msp + (size_t)((rc * 4 + ks) * 4 + quad) * 256;
                bf16x8 wh[2], wl[2];
#pragma unroll
                for (int mt = 0; mt < 2; ++mt) {
                    wh[mt] = *(const bf16x8*)(mb + (mt * 16 + lid) * 8);
                    wl[mt] = *(const bf16x8*)(mb + MSP_PLANE + (mt * 16 + lid) * 8);
                }
#pragma unroll
                for (int mt = 0; mt < 2; ++mt) {
                    pacc[mt] = MFMA16(wh[mt], xh[ks], pacc[mt], 0, 0, 0);
                    pacc[mt] = MFMA16(wh[mt], xl[ks], pacc[mt], 0, 0, 0);
                    pacc[mt] = MFMA16(wl[mt], xh[ks], pacc[mt], 0, 0, 0);
                }
            }
            // epilogue: *ps^2, split, write transposed into y2[buf][.][n][r]
#pragma unroll
            for (int mt = 0; mt < 2; ++mt) {
                const int n = wv * 16 + lid;
                unsigned short hh[4], ll[4];
#pragma unroll
                for (int r = 0; r < 4; ++r) {
                    float yv = pacc[mt][r] * ps2;
                    split2(yv, hh[r], ll[r]);
                }
                bf16x4 hv = {(short)hh[0], (short)hh[1], (short)hh[2], (short)hh[3]};
                bf16x4 lv = {(short)ll[0], (short)ll[1], (short)ll[2], (short)ll[3]};
                *(bf16x4*)&y2[buf][0][n * 40 + mt * 16 + quad * 4] = hv;
                *(bf16x4*)&y2[buf][1][n * 40 + mt * 16 + quad * 4] = lv;
            }
            __syncthreads();
            // ---- scores += x @ y^T over this 32-d chunk (A = held x frags) ----
#pragma unroll
            for (int ntp = 0; ntp < 8; ++ntp) {
                const int yrow = ntp * 16 + lid;
                bf16x8 yh = *(const bf16x8*)&y2[buf][0][yrow * 40 + quad * 8];
                bf16x8 yl = *(const bf16x8*)&y2[buf][1][yrow * 40 + quad * 8];
                sacc[ntp] = MFMA16(xh[rc], yh, sacc[ntp], 0, 0, 0);
                sacc[ntp] = MFMA16(xh[rc], yl, sacc[ntp], 0, 0, 0);
                sacc[ntp] = MFMA16(xl[rc], yh, sacc[ntp], 0, 0, 0);
            }
            // no trailing barrier: next rc writes the OTHER buffer; the
            // following iteration's barrier orders reuse of this one.
        }
    }

    // ---- tk: reduce across the 4 quads (each holds a 32-d slice) ----
    tk += __shfl_xor(tk, 16);
    tk += __shfl_xor(tk, 32);

    // ---- write partial (store mode) or atomic accumulate (fallback) ----
    float* rep = sc + (size_t)(store_mode ? blockIdx.x
                                          : (blockIdx.x & (NREP - 1))) * PSTRIDE;
    if (store_mode) {
#pragma unroll
        for (int ntp = 0; ntp < 8; ++ntp)
#pragma unroll
            for (int r = 0; r < 4; ++r) {
                const int n  = wv * 16 + quad * 4 + r;
                const int np = ntp * 16 + lid;
                rep[n * N_ + np] = sacc[ntp][r];
            }
        if (quad == 0) rep[N_ * N_ + wv * 16 + lid] = tk;
    } else {
#pragma unroll
        for (int ntp = 0; ntp < 8; ++ntp)
#pragma unroll
            for (int r = 0; r < 4; ++r) {
                const int n  = wv * 16 + quad * 4 + r;
                const int np = ntp * 16 + lid;
                atomicAdd(&rep[n * N_ + np], sacc[ntp][r]);
            }
        if (quad == 0) atomicAdd(&rep[N_ * N_ + wv * 16 + lid], tk);
    }
}

// ---------------------------------------------------------------------------
// K2: sum R partials (scores quad-term + tk row), add tk[n'], softmax, write
// attn pre-swizzled into B-frag layout att2[ks][quad][n][j]. grid 128 x 1024.
// ---------------------------------------------------------------------------
__global__ __launch_bounds__(1024) void k_softmax(const float* __restrict__ sc, int R,
                                                  unsigned short* __restrict__ att2) {
    const int n  = blockIdx.x;
    const int t  = threadIdx.x;          // 0..1023
    const int rg = t >> 5;               // 0..31: rep-group
    const int c4 = (t & 31) * 4;         // column quad

    float4 a  = {0.f, 0.f, 0.f, 0.f};
    float4 tk = {0.f, 0.f, 0.f, 0.f};
    for (int rep = rg; rep < R; rep += 32) {
        const size_t base = (size_t)rep * PSTRIDE;
        const float4 p = *(const float4*)&sc[base + n * N_ + c4];
        a.x += p.x; a.y += p.y; a.z += p.z; a.w += p.w;
        const float4 q = *(const float4*)&sc[base + N_ * N_ + c4];
        tk.x += q.x; tk.y += q.y; tk.z += q.z; tk.w += q.w;
    }
    __shared__ float tmp[32][128];
    __shared__ float tmp2[32][128];
    *(float4*)&tmp[rg][c4]  = a;
    *(float4*)&tmp2[rg][c4] = tk;
    __syncthreads();

    __shared__ float red[2];
    __shared__ float red2[2];

    float v = 0.f;
    if (t < 128) {
        float q = 0.f, k = 0.f;
#pragma unroll
        for (int g = 0; g < 32; ++g) { q += tmp[g][t]; k += tmp2[g][t]; }
        v = (q + k) * 0.08838834764831845f;   // 1/sqrt(128)
    }

    float m = v;
#pragma unroll
    for (int o = 32; o > 0; o >>= 1) m = fmaxf(m, __shfl_xor(m, o));
    if (t < 128 && (t & 63) == 0) red[t >> 6] = m;
    __syncthreads();
    m = fmaxf(red[0], red[1]);

    float e = (t < 128) ? expf(v - m) : 0.f;
    float sum = e;
#pragma unroll
    for (int o = 32; o > 0; o >>= 1) sum += __shfl_xor(sum, o);
    if (t < 128 && (t & 63) == 0) red2[t >> 6] = sum;
    __syncthreads();
    sum = red2[0] + red2[1];

    if (t < 128) {
        const int ks = t >> 5, quad = (t >> 3) & 3, j = t & 7;
        att2[(size_t)(((ks * 4 + quad) * 128) + n) * 8 + j] = bf16_rn(e / sum);
    }
}

// ---------------------------------------------------------------------------
// K3: out[n, s*128+r] = sum_n' attn[n,n'] * v_s[n',r]. grid 1024 x 256.
// LDS: vT only (~35KB). Wv from pre-split Wsp (p=2), attn from att2.
// ---------------------------------------------------------------------------
__global__ __launch_bounds__(256, 2) void k_out(const float* __restrict__ x,
                                                const unsigned short* __restrict__ Wsp,
                                                const float* __restrict__ b,
                                                const unsigned short* __restrict__ att2,
                                                const float* __restrict__ peT,
                                                float* __restrict__ out) {
    __shared__ unsigned short vT[128 * 136];     // [r][n'] bf16
    __shared__ float bv[128];

    const int t    = threadIdx.x;
    const int lane = t & 63;
    const int wv   = t >> 6;
    const int lid  = lane & 15;
    const int quad = lane >> 4;
    const int s    = blockIdx.x;
    const float ps = peT[s];

    if (t < 128) bv[t] = b[3 * t + 2];
    __syncthreads();

    const f32x4 fzero = {0.f, 0.f, 0.f, 0.f};

    // ---- held xs A-frags: rows n=(wv*2+mt)*16+lid ----
    bf16x8 xh[2][4], xl[2][4];
#pragma unroll
    for (int mt = 0; mt < 2; ++mt) {
        const int row = (wv * 2 + mt) * 16 + lid;
        const float* xp = x + (size_t)row * SD_ + (size_t)s * D_;
#pragma unroll
        for (int ks = 0; ks < 4; ++ks)
            load_split8(xp + ks * 32 + quad * 8, ps, xh[mt][ks], xl[mt][ks]);
    }

    // ---- v-proj: v = xs @ Wv^T (3-term split); vT chunks disjoint, no syncs ----
    for (int rc = 0; rc < 4; ++rc) {
        f32x4 vacc[2][2];
        vacc[0][0] = fzero; vacc[0][1] = fzero; vacc[1][0] = fzero; vacc[1][1] = fzero;
#pragma unroll
        for (int ks = 0; ks < 4; ++ks) {
            const unsigned short* wb =
                Wsp + (size_t)(((2 * 4 + rc) * 4 + ks) * 4 + quad) * 256;
            bf16x8 wh[2], wl[2];
#pragma unroll
            for (int nt = 0; nt < 2; ++nt) {
                wh[nt] = *(const bf16x8*)(wb + (nt * 16 + lid) * 8);
                wl[nt] = *(const bf16x8*)(wb + WSP_PLANE + (nt * 16 + lid) * 8);
            }
#pragma unroll
            for (int mt = 0; mt < 2; ++mt)
#pragma unroll
                for (int nt = 0; nt < 2; ++nt) {
                    vacc[mt][nt] = MFMA16(xh[mt][ks], wh[nt], vacc[mt][nt], 0, 0, 0);
                    vacc[mt][nt] = MFMA16(xh[mt][ks], wl[nt], vacc[mt][nt], 0, 0, 0);
                    vacc[mt][nt] = MFMA16(xl[mt][ks], wh[nt], vacc[mt][nt], 0, 0, 0);
                }
        }
#pragma unroll
        for (int mt = 0; mt < 2; ++mt)
#pragma unroll
            for (int nt = 0; nt < 2; ++nt) {
                const int r = rc * 32 + nt * 16 + lid;
                const float bias = bv[r];
                unsigned short hh[4];
#pragma unroll
                for (int i = 0; i < 4; ++i) hh[i] = bf16_rn(vacc[mt][nt][i] + bias);
                bf16x4 hv = {(short)hh[0], (short)hh[1], (short)hh[2], (short)hh[3]};
                *(bf16x4*)&vT[r * 136 + (wv * 2 + mt) * 16 + quad * 4] = hv;
            }
    }
    __syncthreads();

    // ---- PV: outT = vT @ attnT (plain bf16, attn B-frags from att2) ----
    {
        f32x4 oacc[2][8];
#pragma unroll
        for (int i = 0; i < 2; ++i)
#pragma unroll
            for (int j = 0; j < 8; ++j) oacc[i][j] = fzero;
#pragma unroll
        for (int ks = 0; ks < 4; ++ks) {
            const int kofs = ks * 32 + quad * 8;
            bf16x8 a[2];
#pragma unroll
            for (int mt = 0; mt < 2; ++mt)
                a[mt] = *(const bf16x8*)&vT[((wv * 2 + mt) * 16 + lid) * 136 + kofs];
#pragma unroll
            for (int nt = 0; nt < 8; ++nt) {
                bf16x8 bb = *(const bf16x8*)&att2[(size_t)(((ks * 4 + quad) * 128) +
                                                           (nt * 16 + lid)) * 8];
#pragma unroll
                for (int mt = 0; mt < 2; ++mt)
                    oacc[mt][nt] = MFMA16(a[mt], bb, oacc[mt][nt], 0, 0, 0);
            }
        }
#pragma unroll
        for (int mt = 0; mt < 2; ++mt)
#pragma unroll
            for (int nt = 0; nt < 8; ++nt) {
                const int r = (wv * 2 + mt) * 16 + quad * 4;
                const int n = nt * 16 + lid;
                *(float4*)&out[(size_t)n * SD_ + (size_t)s * D_ + r] = *(float4*)&oacc[mt][nt];
            }
    }
}

// ---------------------------------------------------------------------------
extern "C" void kernel_launch(void* const* d_in, const int* in_sizes, int n_in,
                              void* d_out, int out_size, void* d_ws, size_t ws_size,
                              hipStream_t stream) {
    const float* x = (const float*)d_in[0];
    const float* W = (const float*)d_in[1];
    const float* b = (const float*)d_in[2];
    float* out = (float*)d_out;

    const size_t store_bytes = (size_t)GRID_SC * PSTRIDE * sizeof(float);  // ~32.3 MiB
    const size_t rep_bytes   = (size_t)NREP * PSTRIDE * sizeof(float);     // ~4.2 MB
    const size_t tail_bytes  = (size_t)N_ * N_ * sizeof(unsigned short)        // att2
                             + (size_t)2 * WSP_PLANE * sizeof(unsigned short)  // Wsp
                             + (size_t)S_ * sizeof(float)                      // peT
                             + (size_t)2 * MSP_PLANE * sizeof(unsigned short)  // Msp
                             + (size_t)N_ * sizeof(float);                     // u
    const int store_mode = (ws_size >= store_bytes + tail_bytes) ? 1 : 0;
    const size_t sc_bytes = store_mode ? store_bytes : rep_bytes;

    // ws layout: scores region | att2 | Wsp | peT | Msp | u
    float* scores        = (float*)d_ws;
    unsigned short* att2 = (unsigned short*)((char*)d_ws + sc_bytes);
    unsigned short* Wsp  = att2 + N_ * N_;
    float* peT           = (float*)(Wsp + 2 * WSP_PLANE);
    unsigned short* Msp  = (unsigned short*)(peT + S_);
    float* uvec          = (float*)(Msp + 2 * MSP_PLANE);

    if (!store_mode)
        hipMemsetAsync(scores, 0, sc_bytes, stream);

    hipLaunchKernelGGL(k_prep,    dim3(192),     dim3(256),  0, stream, W, Wsp, peT);
    hipLaunchKernelGGL(k_prepM,   dim3(128),     dim3(128),  0, stream, W, b, Msp, uvec);
    hipLaunchKernelGGL(k_scores,  dim3(GRID_SC), dim3(512),  0, stream, x, Msp, uvec, peT,
                       scores, store_mode);
    hipLaunchKernelGGL(k_softmax, dim3(N_),      dim3(1024), 0, stream, scores,
                       store_mode ? GRID_SC : NREP, att2);
    hipLaunchKernelGGL(k_out,     dim3(1024),    dim3(256),  0, stream, x, Wsp, b, att2,
                       peT, out);
}

// Round 8
// 288.056 us; speedup vs baseline: 1.3880x; 1.0204x over previous
//
#include <hip/hip_runtime.h>
#include <math.h>

#define N_   128
#define S_   1024
#define D_   128
#define SD_  (S_ * D_)     // 131072

#define WSP_PLANE 49152    // 3*4*4*4*32*8  (one hi or lo W plane, elements)
#define MSP_PLANE 16384    // 4*4*4*32*8    (one hi or lo M plane, elements)
#define NREP 64            // fallback (atomic) replica count
#define SB   2             // s-values per k_scores block
#define GRID_SC (S_ / SB)  // 512
#define PSTRIDE ((N_ + 1) * N_)   // per-partial stride: 128x128 scores + 128 tk row

typedef __attribute__((ext_vector_type(8))) short bf16x8;
typedef __attribute__((ext_vector_type(4))) short bf16x4;
typedef __attribute__((ext_vector_type(4))) float f32x4;
#define MFMA16 __builtin_amdgcn_mfma_f32_16x16x32_bf16

// pe(s): row i = s>>5, col c = s&31; arg = pi*i*1000^(-(c&~1)/128); sin if c even
__device__ __forceinline__ float pe_scale(int s) {
    int i = s >> 5;
    int c = s & 31;
    double rexp = pow(1000.0, -(double)(c & ~1) / 128.0);
    double arg = M_PI * (double)i * rexp;
    return (float)((c & 1) ? cos(arg) : sin(arg));
}

__device__ __forceinline__ unsigned short bf16_rn(float f) {
    unsigned int u = __float_as_uint(f);
    u += 0x7fff + ((u >> 16) & 1);
    return (unsigned short)(u >> 16);
}
__device__ __forceinline__ float bf16_f(unsigned short h) {
    return __uint_as_float(((unsigned int)h) << 16);
}
__device__ __forceinline__ void split2(float f, unsigned short& h, unsigned short& l) {
    h = bf16_rn(f);
    l = bf16_rn(f - bf16_f(h));
}

// load 8 consecutive fp32, scale, split into hi/lo bf16x8 frags (used by k_out)
__device__ __forceinline__ void load_split8(const float* p, float scale,
                                            bf16x8& hi, bf16x8& lo) {
    float4 u0 = *(const float4*)(p);
    float4 u1 = *(const float4*)(p + 4);
    unsigned short h[8], l[8];
    split2(u0.x * scale, h[0], l[0]); split2(u0.y * scale, h[1], l[1]);
    split2(u0.z * scale, h[2], l[2]); split2(u0.w * scale, h[3], l[3]);
    split2(u1.x * scale, h[4], l[4]); split2(u1.y * scale, h[5], l[5]);
    split2(u1.z * scale, h[6], l[6]); split2(u1.w * scale, h[7], l[7]);
    hi = bf16x8{(short)h[0],(short)h[1],(short)h[2],(short)h[3],
                (short)h[4],(short)h[5],(short)h[6],(short)h[7]};
    lo = bf16x8{(short)l[0],(short)l[1],(short)l[2],(short)l[3],
                (short)l[4],(short)l[5],(short)l[6],(short)l[7]};
}

// ---------------------------------------------------------------------------
// K0: split W (fp32 [384][128]) into hi/lo bf16 planes in MFMA-frag-swizzled
// layout Wsp[h][p][rc][ks][quad][m(32)][j(8)]. Also fills pe table (1024 f32).
// grid 192 x 256. (Only p=2 of Wsp is consumed now, by k_out.)
// ---------------------------------------------------------------------------
__global__ __launch_bounds__(256) void k_prep(const float* __restrict__ W,
                                              unsigned short* __restrict__ Wsp,
                                              float* __restrict__ peT) {
    const int idx = blockIdx.x * 256 + threadIdx.x;  // 0..49151
    if (idx < S_) peT[idx] = pe_scale(idx);
    const int rg = idx >> 7;         // W row (feature f)
    const int d  = idx & 127;
    const int p  = rg % 3;
    const int r  = rg / 3;
    const int rc = r >> 5, m = r & 31;
    const int ks = d >> 5, quad = (d >> 3) & 3, j = d & 7;
    unsigned short h, l;
    split2(W[idx], h, l);
    const size_t off = (size_t)((((p * 4 + rc) * 4 + ks) * 4 + quad) * 32 + m) * 8 + j;
    Wsp[off] = h;
    Wsp[off + WSP_PLANE] = l;
}

// ---------------------------------------------------------------------------
// K0b: M = Wq^T Wk (fp32, M[dp][e] = sum_g W[3g][dp]*W[3g+1][e]) split into
// hi/lo planes in frag-swizzled layout Msp[rc][ks][quad][m(32)][j(8)], and
// u[e] = sum_g b[3g]*W[3g+1][e]. grid 128 x 128.
// ---------------------------------------------------------------------------
__global__ __launch_bounds__(128) void k_prepM(const float* __restrict__ W,
                                               const float* __restrict__ b,
                                               unsigned short* __restrict__ Msp,
                                               float* __restrict__ uo) {
    const int dp = blockIdx.x;      // output row d'
    const int e  = threadIdx.x;     // input col e
    float acc = 0.f;
#pragma unroll 4
    for (int g = 0; g < 128; ++g)
        acc += W[(3 * g) * 128 + dp] * W[(3 * g + 1) * 128 + e];
    unsigned short h, l;
    split2(acc, h, l);
    const int rc = dp >> 5, m = dp & 31;
    const int ks = e >> 5, quad = (e >> 3) & 3, j = e & 7;
    const size_t off = (size_t)(((rc * 4 + ks) * 4 + quad) * 32 + m) * 8 + j;
    Msp[off] = h;
    Msp[off + MSP_PLANE] = l;
    if (blockIdx.x == 0) {
        float ua = 0.f;
#pragma unroll 4
        for (int g = 0; g < 128; ++g)
            ua += b[3 * g] * W[(3 * g + 1) * 128 + e];
        uo[e] = ua;
    }
}

// ---------------------------------------------------------------------------
// K1: partial scores via the M-restructure:
//   scores[n,n'] = sum_s x[n,s]^T (ps^2 M) x[n',s]  + tk[n']   (row-constant
//   terms dropped: softmax-invariant).
// Per ss: one projection y = (ps^2 M) x (3-term split MFMA), y through
// ping-pong LDS (ONE barrier per rc), score A-operand = held raw-x frags.
// tk[n'] = sum_s ps*(u . x[n',s]) accumulated in fp32 during the x load,
// stored as row 128 of the partial. grid GRID_SC x 512.
// __launch_bounds__(512, 1): VGPR cap 512 — peak live state is ~110-160 VGPRs.
// History: (512,4) capped at 64 -> ~280 MB/dir scratch spill (R6);
// (512,2) still chose the 128-reg occupancy tier and spilled ~134 MB/dir
// (R7). Force the spill-free allocation; 8 waves/CU is acceptable.
// ---------------------------------------------------------------------------
__global__ __launch_bounds__(512, 1) void k_scores(const float* __restrict__ x,
                                                   const unsigned short* __restrict__ Msp,
                                                   const float* __restrict__ u,
                                                   const float* __restrict__ peT,
                                                   float* __restrict__ sc,
                                                   int store_mode) {
    __shared__ unsigned short y2[2][2][128 * 40];   // [buf][hi/lo] : [n][r]
    __shared__ float ul[128];

    const int t    = threadIdx.x;
    const int lane = t & 63;
    const int wv   = t >> 6;        // wave 0..7
    const int lid  = lane & 15;
    const int quad = lane >> 4;

    if (t < 128) ul[t] = u[t];
    __syncthreads();

    const f32x4 fzero = {0.f, 0.f, 0.f, 0.f};
    f32x4 sacc[8];
#pragma unroll
    for (int j = 0; j < 8; ++j) sacc[j] = fzero;
    float tk = 0.f;

    for (int ss = 0; ss < SB; ++ss) {
        const int s = blockIdx.x * SB + ss;
        const float ps = peT[s];
        const float ps2 = ps * ps;

        // ---- held RAW x frags (rows n=wv*16+lid, k=ks*32+quad*8) + u-dot ----
        bf16x8 xh[4], xl[4];
        {
            const int row = wv * 16 + lid;
            const float* xp = x + (size_t)row * SD_ + (size_t)s * D_;
            float dot = 0.f;
#pragma unroll
            for (int ks = 0; ks < 4; ++ks) {
                const float* pp = xp + ks * 32 + quad * 8;
                float4 u0 = *(const float4*)pp;
                float4 u1 = *(const float4*)(pp + 4);
                const float* uu = &ul[ks * 32 + quad * 8];
                dot += u0.x * uu[0] + u0.y * uu[1] + u0.z * uu[2] + u0.w * uu[3]
                     + u1.x * uu[4] + u1.y * uu[5] + u1.z * uu[6] + u1.w * uu[7];
                unsigned short h[8], l[8];
                split2(u0.x, h[0], l[0]); split2(u0.y, h[1], l[1]);
                split2(u0.z, h[2], l[2]); split2(u0.w, h[3], l[3]);
                split2(u1.x, h[4], l[4]); split2(u1.y, h[5], l[5]);
                split2(u1.z, h[6], l[6]); split2(u1.w, h[7], l[7]);
                xh[ks] = bf16x8{(short)h[0],(short)h[1],(short)h[2],(short)h[3],
                                (short)h[4],(short)h[5],(short)h[6],(short)h[7]};
                xl[ks] = bf16x8{(short)l[0],(short)l[1],(short)l[2],(short)l[3],
                                (short)l[4],(short)l[5],(short)l[6],(short)l[7]};
            }
            tk += ps * dot;
        }

#pragma unroll
        for (int rc = 0; rc < 4; ++rc) {
            const int buf = rc & 1;   // ping-pong (ss*4 is even)
            // ---- projection: y rows rc*32..+32 = M @ x (3-term split) ----
            f32x4 pacc[2];
            pacc[0] = fzero; pacc[1] = fzero;
#pragma unroll
            for (int ks = 0; ks < 4; ++ks) {
                const unsigned short* mb =
                    Msp + (size_t)((rc * 4 + ks) * 4 + quad) * 256;
                bf16x8 wh[2], wl[2];
#pragma unroll
                for (int mt = 0; mt < 2; ++mt) {
                    wh[mt] = *(const bf16x8*)(mb + (mt * 16 + lid) * 8);
                    wl[mt] = *(const bf16x8*)(mb + MSP_PLANE + (mt * 16 + lid) * 8);
                }
#pragma unroll
                for (int mt = 0; mt < 2; ++mt) {
                    pacc[mt] = MFMA16(wh[mt], xh[ks], pacc[mt], 0, 0, 0);
                    pacc[mt] = MFMA16(wh[mt], xl[ks], pacc[mt], 0, 0, 0);
                    pacc[mt] = MFMA16(wl[mt], xh[ks], pacc[mt], 0, 0, 0);
                }
            }
            // epilogue: *ps^2, split, write transposed into y2[buf][.][n][r]
#pragma unroll
            for (int mt = 0; mt < 2; ++mt) {
                const int n = wv * 16 + lid;
                unsigned short hh[4], ll[4];
#pragma unroll
                for (int r = 0; r < 4; ++r) {
                    float yv = pacc[mt][r] * ps2;
                    split2(yv, hh[r], ll[r]);
                }
                bf16x4 hv = {(short)hh[0], (short)hh[1], (short)hh[2], (short)hh[3]};
                bf16x4 lv = {(short)ll[0], (short)ll[1], (short)ll[2], (short)ll[3]};
                *(bf16x4*)&y2[buf][0][n * 40 + mt * 16 + quad * 4] = hv;
                *(bf16x4*)&y2[buf][1][n * 40 + mt * 16 + quad * 4] = lv;
            }
            __syncthreads();
            // ---- scores += x @ y^T over this 32-d chunk (A = held x frags) ----
#pragma unroll
            for (int ntp = 0; ntp < 8; ++ntp) {
                const int yrow = ntp * 16 + lid;
                bf16x8 yh = *(const bf16x8*)&y2[buf][0][yrow * 40 + quad * 8];
                bf16x8 yl = *(const bf16x8*)&y2[buf][1][yrow * 40 + quad * 8];
                sacc[ntp] = MFMA16(xh[rc], yh, sacc[ntp], 0, 0, 0);
                sacc[ntp] = MFMA16(xh[rc], yl, sacc[ntp], 0, 0, 0);
                sacc[ntp] = MFMA16(xl[rc], yh, sacc[ntp], 0, 0, 0);
            }
            // no trailing barrier: next rc writes the OTHER buffer; the
            // following iteration's barrier orders reuse of this one.
        }
    }

    // ---- tk: reduce across the 4 quads (each holds a 32-d slice) ----
    tk += __shfl_xor(tk, 16);
    tk += __shfl_xor(tk, 32);

    // ---- write partial (store mode) or atomic accumulate (fallback) ----
    float* rep = sc + (size_t)(store_mode ? blockIdx.x
                                          : (blockIdx.x & (NREP - 1))) * PSTRIDE;
    if (store_mode) {
#pragma unroll
        for (int ntp = 0; ntp < 8; ++ntp)
#pragma unroll
            for (int r = 0; r < 4; ++r) {
                const int n  = wv * 16 + quad * 4 + r;
                const int np = ntp * 16 + lid;
                rep[n * N_ + np] = sacc[ntp][r];
            }
        if (quad == 0) rep[N_ * N_ + wv * 16 + lid] = tk;
    } else {
#pragma unroll
        for (int ntp = 0; ntp < 8; ++ntp)
#pragma unroll
            for (int r = 0; r < 4; ++r) {
                const int n  = wv * 16 + quad * 4 + r;
                const int np = ntp * 16 + lid;
                atomicAdd(&rep[n * N_ + np], sacc[ntp][r]);
            }
        if (quad == 0) atomicAdd(&rep[N_ * N_ + wv * 16 + lid], tk);
    }
}

// ---------------------------------------------------------------------------
// K2: sum R partials (scores quad-term + tk row), add tk[n'], softmax, write
// attn pre-swizzled into B-frag layout att2[ks][quad][n][j]. grid 128 x 1024.
// ---------------------------------------------------------------------------
__global__ __launch_bounds__(1024) void k_softmax(const float* __restrict__ sc, int R,
                                                  unsigned short* __restrict__ att2) {
    const int n  = blockIdx.x;
    const int t  = threadIdx.x;          // 0..1023
    const int rg = t >> 5;               // 0..31: rep-group
    const int c4 = (t & 31) * 4;         // column quad

    float4 a  = {0.f, 0.f, 0.f, 0.f};
    float4 tk = {0.f, 0.f, 0.f, 0.f};
    for (int rep = rg; rep < R; rep += 32) {
        const size_t base = (size_t)rep * PSTRIDE;
        const float4 p = *(const float4*)&sc[base + n * N_ + c4];
        a.x += p.x; a.y += p.y; a.z += p.z; a.w += p.w;
        const float4 q = *(const float4*)&sc[base + N_ * N_ + c4];
        tk.x += q.x; tk.y += q.y; tk.z += q.z; tk.w += q.w;
    }
    __shared__ float tmp[32][128];
    __shared__ float tmp2[32][128];
    *(float4*)&tmp[rg][c4]  = a;
    *(float4*)&tmp2[rg][c4] = tk;
    __syncthreads();

    __shared__ float red[2];
    __shared__ float red2[2];

    float v = 0.f;
    if (t < 128) {
        float q = 0.f, k = 0.f;
#pragma unroll
        for (int g = 0; g < 32; ++g) { q += tmp[g][t]; k += tmp2[g][t]; }
        v = (q + k) * 0.08838834764831845f;   // 1/sqrt(128)
    }

    float m = v;
#pragma unroll
    for (int o = 32; o > 0; o >>= 1) m = fmaxf(m, __shfl_xor(m, o));
    if (t < 128 && (t & 63) == 0) red[t >> 6] = m;
    __syncthreads();
    m = fmaxf(red[0], red[1]);

    float e = (t < 128) ? expf(v - m) : 0.f;
    float sum = e;
#pragma unroll
    for (int o = 32; o > 0; o >>= 1) sum += __shfl_xor(sum, o);
    if (t < 128 && (t & 63) == 0) red2[t >> 6] = sum;
    __syncthreads();
    sum = red2[0] + red2[1];

    if (t < 128) {
        const int ks = t >> 5, quad = (t >> 3) & 3, j = t & 7;
        att2[(size_t)(((ks * 4 + quad) * 128) + n) * 8 + j] = bf16_rn(e / sum);
    }
}

// ---------------------------------------------------------------------------
// K3: out[n, s*128+r] = sum_n' attn[n,n'] * v_s[n',r]. grid 1024 x 256.
// LDS: vT only (~35KB). Wv from pre-split Wsp (p=2), attn from att2.
// ---------------------------------------------------------------------------
__global__ __launch_bounds__(256, 2) void k_out(const float* __restrict__ x,
                                                const unsigned short* __restrict__ Wsp,
                                                const float* __restrict__ b,
                                                const unsigned short* __restrict__ att2,
                                                const float* __restrict__ peT,
                                                float* __restrict__ out) {
    __shared__ unsigned short vT[128 * 136];     // [r][n'] bf16
    __shared__ float bv[128];

    const int t    = threadIdx.x;
    const int lane = t & 63;
    const int wv   = t >> 6;
    const int lid  = lane & 15;
    const int quad = lane >> 4;
    const int s    = blockIdx.x;
    const float ps = peT[s];

    if (t < 128) bv[t] = b[3 * t + 2];
    __syncthreads();

    const f32x4 fzero = {0.f, 0.f, 0.f, 0.f};

    // ---- held xs A-frags: rows n=(wv*2+mt)*16+lid ----
    bf16x8 xh[2][4], xl[2][4];
#pragma unroll
    for (int mt = 0; mt < 2; ++mt) {
        const int row = (wv * 2 + mt) * 16 + lid;
        const float* xp = x + (size_t)row * SD_ + (size_t)s * D_;
#pragma unroll
        for (int ks = 0; ks < 4; ++ks)
            load_split8(xp + ks * 32 + quad * 8, ps, xh[mt][ks], xl[mt][ks]);
    }

    // ---- v-proj: v = xs @ Wv^T (3-term split); vT chunks disjoint, no syncs ----
    for (int rc = 0; rc < 4; ++rc) {
        f32x4 vacc[2][2];
        vacc[0][0] = fzero; vacc[0][1] = fzero; vacc[1][0] = fzero; vacc[1][1] = fzero;
#pragma unroll
        for (int ks = 0; ks < 4; ++ks) {
            const unsigned short* wb =
                Wsp + (size_t)(((2 * 4 + rc) * 4 + ks) * 4 + quad) * 256;
            bf16x8 wh[2], wl[2];
#pragma unroll
            for (int nt = 0; nt < 2; ++nt) {
                wh[nt] = *(const bf16x8*)(wb + (nt * 16 + lid) * 8);
                wl[nt] = *(const bf16x8*)(wb + WSP_PLANE + (nt * 16 + lid) * 8);
            }
#pragma unroll
            for (int mt = 0; mt < 2; ++mt)
#pragma unroll
                for (int nt = 0; nt < 2; ++nt) {
                    vacc[mt][nt] = MFMA16(xh[mt][ks], wh[nt], vacc[mt][nt], 0, 0, 0);
                    vacc[mt][nt] = MFMA16(xh[mt][ks], wl[nt], vacc[mt][nt], 0, 0, 0);
                    vacc[mt][nt] = MFMA16(xl[mt][ks], wh[nt], vacc[mt][nt], 0, 0, 0);
                }
        }
#pragma unroll
        for (int mt = 0; mt < 2; ++mt)
#pragma unroll
            for (int nt = 0; nt < 2; ++nt) {
                const int r = rc * 32 + nt * 16 + lid;
                const float bias = bv[r];
                unsigned short hh[4];
#pragma unroll
                for (int i = 0; i < 4; ++i) hh[i] = bf16_rn(vacc[mt][nt][i] + bias);
                bf16x4 hv = {(short)hh[0], (short)hh[1], (short)hh[2], (short)hh[3]};
                *(bf16x4*)&vT[r * 136 + (wv * 2 + mt) * 16 + quad * 4] = hv;
            }
    }
    __syncthreads();

    // ---- PV: outT = vT @ attnT (plain bf16, attn B-frags from att2) ----
    {
        f32x4 oacc[2][8];
#pragma unroll
        for (int i = 0; i < 2; ++i)
#pragma unroll
            for (int j = 0; j < 8; ++j) oacc[i][j] = fzero;
#pragma unroll
        for (int ks = 0; ks < 4; ++ks) {
            const int kofs = ks * 32 + quad * 8;
            bf16x8 a[2];
#pragma unroll
            for (int mt = 0; mt < 2; ++mt)
                a[mt] = *(const bf16x8*)&vT[((wv * 2 + mt) * 16 + lid) * 136 + kofs];
#pragma unroll
            for (int nt = 0; nt < 8; ++nt) {
                bf16x8 bb = *(const bf16x8*)&att2[(size_t)(((ks * 4 + quad) * 128) +
                                                           (nt * 16 + lid)) * 8];
#pragma unroll
                for (int mt = 0; mt < 2; ++mt)
                    oacc[mt][nt] = MFMA16(a[mt], bb, oacc[mt][nt], 0, 0, 0);
            }
        }
#pragma unroll
        for (int mt = 0; mt < 2; ++mt)
#pragma unroll
            for (int nt = 0; nt < 8; ++nt) {
                const int r = (wv * 2 + mt) * 16 + quad * 4;
                const int n = nt * 16 + lid;
                *(float4*)&out[(size_t)n * SD_ + (size_t)s * D_ + r] = *(float4*)&oacc[mt][nt];
            }
    }
}

// ---------------------------------------------------------------------------
extern "C" void kernel_launch(void* const* d_in, const int* in_sizes, int n_in,
                              void* d_out, int out_size, void* d_ws, size_t ws_size,
                              hipStream_t stream) {
    const float* x = (const float*)d_in[0];
    const float* W = (const float*)d_in[1];
    const float* b = (const float*)d_in[2];
    float* out = (float*)d_out;

    const size_t store_bytes = (size_t)GRID_SC * PSTRIDE * sizeof(float);  // ~32.3 MiB
    const size_t rep_bytes   = (size_t)NREP * PSTRIDE * sizeof(float);     // ~4.2 MB
    const size_t tail_bytes  = (size_t)N_ * N_ * sizeof(unsigned short)        // att2
                             + (size_t)2 * WSP_PLANE * sizeof(unsigned short)  // Wsp
                             + (size_t)S_ * sizeof(float)                      // peT
                             + (size_t)2 * MSP_PLANE * sizeof(unsigned short)  // Msp
                             + (size_t)N_ * sizeof(float);                     // u
    const int store_mode = (ws_size >= store_bytes + tail_bytes) ? 1 : 0;
    const size_t sc_bytes = store_mode ? store_bytes : rep_bytes;

    // ws layout: scores region | att2 | Wsp | peT | Msp | u
    float* scores        = (float*)d_ws;
    unsigned short* att2 = (unsigned short*)((char*)d_ws + sc_bytes);
    unsigned short* Wsp  = att2 + N_ * N_;
    float* peT           = (float*)(Wsp + 2 * WSP_PLANE);
    unsigned short* Msp  = (unsigned short*)(peT + S_);
    float* uvec          = (float*)(Msp + 2 * MSP_PLANE);

    if (!store_mode)
        hipMemsetAsync(scores, 0, sc_bytes, stream);

    hipLaunchKernelGGL(k_prep,    dim3(192),     dim3(256),  0, stream, W, Wsp, peT);
    hipLaunchKernelGGL(k_prepM,   dim3(128),     dim3(128),  0, stream, W, b, Msp, uvec);
    hipLaunchKernelGGL(k_scores,  dim3(GRID_SC), dim3(512),  0, stream, x, Msp, uvec, peT,
                       scores, store_mode);
    hipLaunchKernelGGL(k_softmax, dim3(N_),      dim3(1024), 0, stream, scores,
                       store_mode ? GRID_SC : NREP, att2);
    hipLaunchKernelGGL(k_out,     dim3(1024),    dim3(256),  0, stream, x, Wsp, b, att2,
                       peT, out);
}

// Round 9
// 277.567 us; speedup vs baseline: 1.4404x; 1.0378x over previous
//
#include <hip/hip_runtime.h>
#include <math.h>

#define N_   128
#define S_   1024
#define D_   128
#define SD_  (S_ * D_)     // 131072

#define WSP_PLANE 49152    // 3*4*4*4*32*8  (one hi or lo W plane, elements)
#define MSP_PLANE 16384    // 4*4*4*32*8    (one hi or lo M plane, elements)
#define NREP 64            // fallback (atomic) replica count
#define SB   2             // s-values per k_scores block
#define GRID_SC (S_ / SB)  // 512
#define PSTRIDE ((N_ + 1) * N_)   // per-partial stride: 128x128 scores + 128 tk row

typedef __attribute__((ext_vector_type(8))) short bf16x8;
typedef __attribute__((ext_vector_type(4))) short bf16x4;
typedef __attribute__((ext_vector_type(4))) float f32x4;
#define MFMA16 __builtin_amdgcn_mfma_f32_16x16x32_bf16

// pe(s): row i = s>>5, col c = s&31; arg = pi*i*1000^(-(c&~1)/128); sin if c even
__device__ __forceinline__ float pe_scale(int s) {
    int i = s >> 5;
    int c = s & 31;
    double rexp = pow(1000.0, -(double)(c & ~1) / 128.0);
    double arg = M_PI * (double)i * rexp;
    return (float)((c & 1) ? cos(arg) : sin(arg));
}

__device__ __forceinline__ unsigned short bf16_rn(float f) {
    unsigned int u = __float_as_uint(f);
    u += 0x7fff + ((u >> 16) & 1);
    return (unsigned short)(u >> 16);
}
__device__ __forceinline__ float bf16_f(unsigned short h) {
    return __uint_as_float(((unsigned int)h) << 16);
}
__device__ __forceinline__ void split2(float f, unsigned short& h, unsigned short& l) {
    h = bf16_rn(f);
    l = bf16_rn(f - bf16_f(h));
}

// load 8 consecutive fp32, scale, split into hi/lo bf16x8 frags (used by k_out)
__device__ __forceinline__ void load_split8(const float* p, float scale,
                                            bf16x8& hi, bf16x8& lo) {
    float4 u0 = *(const float4*)(p);
    float4 u1 = *(const float4*)(p + 4);
    unsigned short h[8], l[8];
    split2(u0.x * scale, h[0], l[0]); split2(u0.y * scale, h[1], l[1]);
    split2(u0.z * scale, h[2], l[2]); split2(u0.w * scale, h[3], l[3]);
    split2(u1.x * scale, h[4], l[4]); split2(u1.y * scale, h[5], l[5]);
    split2(u1.z * scale, h[6], l[6]); split2(u1.w * scale, h[7], l[7]);
    hi = bf16x8{(short)h[0],(short)h[1],(short)h[2],(short)h[3],
                (short)h[4],(short)h[5],(short)h[6],(short)h[7]};
    lo = bf16x8{(short)l[0],(short)l[1],(short)l[2],(short)l[3],
                (short)l[4],(short)l[5],(short)l[6],(short)l[7]};
}

// ---------------------------------------------------------------------------
// K0: split W (fp32 [384][128]) into hi/lo bf16 planes in MFMA-frag-swizzled
// layout Wsp[h][p][rc][ks][quad][m(32)][j(8)]. Also fills pe table (1024 f32).
// grid 192 x 256. (Only p=2 of Wsp is consumed now, by k_out.)
// ---------------------------------------------------------------------------
__global__ __launch_bounds__(256) void k_prep(const float* __restrict__ W,
                                              unsigned short* __restrict__ Wsp,
                                              float* __restrict__ peT) {
    const int idx = blockIdx.x * 256 + threadIdx.x;  // 0..49151
    if (idx < S_) peT[idx] = pe_scale(idx);
    const int rg = idx >> 7;         // W row (feature f)
    const int d  = idx & 127;
    const int p  = rg % 3;
    const int r  = rg / 3;
    const int rc = r >> 5, m = r & 31;
    const int ks = d >> 5, quad = (d >> 3) & 3, j = d & 7;
    unsigned short h, l;
    split2(W[idx], h, l);
    const size_t off = (size_t)((((p * 4 + rc) * 4 + ks) * 4 + quad) * 32 + m) * 8 + j;
    Wsp[off] = h;
    Wsp[off + WSP_PLANE] = l;
}

// ---------------------------------------------------------------------------
// K0b: M = Wq^T Wk (fp32, M[dp][e] = sum_g W[3g][dp]*W[3g+1][e]) split into
// hi/lo planes in frag-swizzled layout Msp[rc][ks][quad][m(32)][j(8)], and
// u[e] = sum_g b[3g]*W[3g+1][e]. grid 128 x 128.
// ---------------------------------------------------------------------------
__global__ __launch_bounds__(128) void k_prepM(const float* __restrict__ W,
                                               const float* __restrict__ b,
                                               unsigned short* __restrict__ Msp,
                                               float* __restrict__ uo) {
    const int dp = blockIdx.x;      // output row d'
    const int e  = threadIdx.x;     // input col e
    float acc = 0.f;
#pragma unroll 4
    for (int g = 0; g < 128; ++g)
        acc += W[(3 * g) * 128 + dp] * W[(3 * g + 1) * 128 + e];
    unsigned short h, l;
    split2(acc, h, l);
    const int rc = dp >> 5, m = dp & 31;
    const int ks = e >> 5, quad = (e >> 3) & 3, j = e & 7;
    const size_t off = (size_t)(((rc * 4 + ks) * 4 + quad) * 32 + m) * 8 + j;
    Msp[off] = h;
    Msp[off + MSP_PLANE] = l;
    if (blockIdx.x == 0) {
        float ua = 0.f;
#pragma unroll 4
        for (int g = 0; g < 128; ++g)
            ua += b[3 * g] * W[(3 * g + 1) * 128 + e];
        uo[e] = ua;
    }
}

// ---------------------------------------------------------------------------
// rc_step<RC>: one 32-row chunk of the M-restructured score update, with ALL
// register-array indices compile-time constants (rule #20: the R6-R8 scratch
// traffic was xh[rc]/xl[rc] runtime-indexed when the rc loop didn't unroll —
// the whole frag arrays went to local memory, immune to __launch_bounds__).
// ---------------------------------------------------------------------------
template <int RC>
__device__ __forceinline__ void rc_step(const unsigned short* __restrict__ Msp,
                                        unsigned short (&y2)[2][2][128 * 40],
                                        const bf16x8 (&xh)[4], const bf16x8 (&xl)[4],
                                        f32x4 (&sacc)[8], float ps2,
                                        int wv, int lid, int quad) {
    constexpr int BUF = RC & 1;   // ping-pong buffer
    const f32x4 fzero = {0.f, 0.f, 0.f, 0.f};

    // ---- projection: y rows RC*32..+32 = M @ x (3-term split) ----
    f32x4 pacc[2];
    pacc[0] = fzero; pacc[1] = fzero;
#pragma unroll
    for (int ks = 0; ks < 4; ++ks) {
        const unsigned short* mb = Msp + (size_t)((RC * 4 + ks) * 4 + quad) * 256;
        bf16x8 wh[2], wl[2];
#pragma unroll
        for (int mt = 0; mt < 2; ++mt) {
            wh[mt] = *(const bf16x8*)(mb + (mt * 16 + lid) * 8);
            wl[mt] = *(const bf16x8*)(mb + MSP_PLANE + (mt * 16 + lid) * 8);
        }
#pragma unroll
        for (int mt = 0; mt < 2; ++mt) {
            pacc[mt] = MFMA16(wh[mt], xh[ks], pacc[mt], 0, 0, 0);
            pacc[mt] = MFMA16(wh[mt], xl[ks], pacc[mt], 0, 0, 0);
            pacc[mt] = MFMA16(wl[mt], xh[ks], pacc[mt], 0, 0, 0);
        }
    }
    // epilogue: *ps^2, split, write transposed into y2[BUF][.][n][r]
#pragma unroll
    for (int mt = 0; mt < 2; ++mt) {
        const int n = wv * 16 + lid;
        unsigned short hh[4], ll[4];
#pragma unroll
        for (int r = 0; r < 4; ++r) {
            float yv = pacc[mt][r] * ps2;
            split2(yv, hh[r], ll[r]);
        }
        bf16x4 hv = {(short)hh[0], (short)hh[1], (short)hh[2], (short)hh[3]};
        bf16x4 lv = {(short)ll[0], (short)ll[1], (short)ll[2], (short)ll[3]};
        *(bf16x4*)&y2[BUF][0][n * 40 + mt * 16 + quad * 4] = hv;
        *(bf16x4*)&y2[BUF][1][n * 40 + mt * 16 + quad * 4] = lv;
    }
    __syncthreads();
    // ---- scores += x @ y^T over this 32-d chunk (A = held x frags) ----
#pragma unroll
    for (int ntp = 0; ntp < 8; ++ntp) {
        const int yrow = ntp * 16 + lid;
        bf16x8 yh = *(const bf16x8*)&y2[BUF][0][yrow * 40 + quad * 8];
        bf16x8 yl = *(const bf16x8*)&y2[BUF][1][yrow * 40 + quad * 8];
        sacc[ntp] = MFMA16(xh[RC], yh, sacc[ntp], 0, 0, 0);
        sacc[ntp] = MFMA16(xh[RC], yl, sacc[ntp], 0, 0, 0);
        sacc[ntp] = MFMA16(xl[RC], yh, sacc[ntp], 0, 0, 0);
    }
    // no trailing barrier: the next rc_step writes the OTHER buffer; its
    // barrier orders reuse of this one.
}

// ---------------------------------------------------------------------------
// K1: partial scores via the M-restructure:
//   scores[n,n'] = sum_s x[n,s]^T (ps^2 M) x[n',s] + tk[n']  (row-constant
//   terms dropped: softmax-invariant). grid GRID_SC x 512.
// __launch_bounds__(512, 2): static-indexed liveness ~113 VGPR fits the
// 128-reg tier -> 2 blocks/CU, no spill expected.
// ---------------------------------------------------------------------------
__global__ __launch_bounds__(512, 2) void k_scores(const float* __restrict__ x,
                                                   const unsigned short* __restrict__ Msp,
                                                   const float* __restrict__ u,
                                                   const float* __restrict__ peT,
                                                   float* __restrict__ sc,
                                                   int store_mode) {
    __shared__ unsigned short y2[2][2][128 * 40];   // [buf][hi/lo] : [n][r]
    __shared__ float ul[128];

    const int t    = threadIdx.x;
    const int lane = t & 63;
    const int wv   = t >> 6;        // wave 0..7
    const int lid  = lane & 15;
    const int quad = lane >> 4;

    if (t < 128) ul[t] = u[t];
    __syncthreads();

    const f32x4 fzero = {0.f, 0.f, 0.f, 0.f};
    f32x4 sacc[8];
#pragma unroll
    for (int j = 0; j < 8; ++j) sacc[j] = fzero;
    float tk = 0.f;

    for (int ss = 0; ss < SB; ++ss) {
        const int s = blockIdx.x * SB + ss;
        const float ps = peT[s];
        const float ps2 = ps * ps;

        // ---- held RAW x frags (rows n=wv*16+lid, k=ks*32+quad*8) + u-dot ----
        bf16x8 xh[4], xl[4];
        {
            const int row = wv * 16 + lid;
            const float* xp = x + (size_t)row * SD_ + (size_t)s * D_;
            float dot = 0.f;
#pragma unroll
            for (int ks = 0; ks < 4; ++ks) {
                const float* pp = xp + ks * 32 + quad * 8;
                float4 u0 = *(const float4*)pp;
                float4 u1 = *(const float4*)(pp + 4);
                const float* uu = &ul[ks * 32 + quad * 8];
                dot += u0.x * uu[0] + u0.y * uu[1] + u0.z * uu[2] + u0.w * uu[3]
                     + u1.x * uu[4] + u1.y * uu[5] + u1.z * uu[6] + u1.w * uu[7];
                unsigned short h[8], l[8];
                split2(u0.x, h[0], l[0]); split2(u0.y, h[1], l[1]);
                split2(u0.z, h[2], l[2]); split2(u0.w, h[3], l[3]);
                split2(u1.x, h[4], l[4]); split2(u1.y, h[5], l[5]);
                split2(u1.z, h[6], l[6]); split2(u1.w, h[7], l[7]);
                xh[ks] = bf16x8{(short)h[0],(short)h[1],(short)h[2],(short)h[3],
                                (short)h[4],(short)h[5],(short)h[6],(short)h[7]};
                xl[ks] = bf16x8{(short)l[0],(short)l[1],(short)l[2],(short)l[3],
                                (short)l[4],(short)l[5],(short)l[6],(short)l[7]};
            }
            tk += ps * dot;
        }

        // ---- four 32-row chunks, fully static indexing ----
        rc_step<0>(Msp, y2, xh, xl, sacc, ps2, wv, lid, quad);
        rc_step<1>(Msp, y2, xh, xl, sacc, ps2, wv, lid, quad);
        rc_step<2>(Msp, y2, xh, xl, sacc, ps2, wv, lid, quad);
        rc_step<3>(Msp, y2, xh, xl, sacc, ps2, wv, lid, quad);
    }

    // ---- tk: reduce across the 4 quads (each holds a 32-d slice) ----
    tk += __shfl_xor(tk, 16);
    tk += __shfl_xor(tk, 32);

    // ---- write partial (store mode) or atomic accumulate (fallback) ----
    float* rep = sc + (size_t)(store_mode ? blockIdx.x
                                          : (blockIdx.x & (NREP - 1))) * PSTRIDE;
    if (store_mode) {
#pragma unroll
        for (int ntp = 0; ntp < 8; ++ntp)
#pragma unroll
            for (int r = 0; r < 4; ++r) {
                const int n  = wv * 16 + quad * 4 + r;
                const int np = ntp * 16 + lid;
                rep[n * N_ + np] = sacc[ntp][r];
            }
        if (quad == 0) rep[N_ * N_ + wv * 16 + lid] = tk;
    } else {
#pragma unroll
        for (int ntp = 0; ntp < 8; ++ntp)
#pragma unroll
            for (int r = 0; r < 4; ++r) {
                const int n  = wv * 16 + quad * 4 + r;
                const int np = ntp * 16 + lid;
                atomicAdd(&rep[n * N_ + np], sacc[ntp][r]);
            }
        if (quad == 0) atomicAdd(&rep[N_ * N_ + wv * 16 + lid], tk);
    }
}

// ---------------------------------------------------------------------------
// K2: sum R partials (scores quad-term + tk row), add tk[n'], softmax, write
// attn pre-swizzled into B-frag layout att2[ks][quad][n][j]. grid 128 x 1024.
// ---------------------------------------------------------------------------
__global__ __launch_bounds__(1024) void k_softmax(const float* __restrict__ sc, int R,
                                                  unsigned short* __restrict__ att2) {
    const int n  = blockIdx.x;
    const int t  = threadIdx.x;          // 0..1023
    const int rg = t >> 5;               // 0..31: rep-group
    const int c4 = (t & 31) * 4;         // column quad

    float4 a  = {0.f, 0.f, 0.f, 0.f};
    float4 tk = {0.f, 0.f, 0.f, 0.f};
    for (int rep = rg; rep < R; rep += 32) {
        const size_t base = (size_t)rep * PSTRIDE;
        const float4 p = *(const float4*)&sc[base + n * N_ + c4];
        a.x += p.x; a.y += p.y; a.z += p.z; a.w += p.w;
        const float4 q = *(const float4*)&sc[base + N_ * N_ + c4];
        tk.x += q.x; tk.y += q.y; tk.z += q.z; tk.w += q.w;
    }
    __shared__ float tmp[32][128];
    __shared__ float tmp2[32][128];
    *(float4*)&tmp[rg][c4]  = a;
    *(float4*)&tmp2[rg][c4] = tk;
    __syncthreads();

    __shared__ float red[2];
    __shared__ float red2[2];

    float v = 0.f;
    if (t < 128) {
        float q = 0.f, k = 0.f;
#pragma unroll
        for (int g = 0; g < 32; ++g) { q += tmp[g][t]; k += tmp2[g][t]; }
        v = (q + k) * 0.08838834764831845f;   // 1/sqrt(128)
    }

    float m = v;
#pragma unroll
    for (int o = 32; o > 0; o >>= 1) m = fmaxf(m, __shfl_xor(m, o));
    if (t < 128 && (t & 63) == 0) red[t >> 6] = m;
    __syncthreads();
    m = fmaxf(red[0], red[1]);

    float e = (t < 128) ? expf(v - m) : 0.f;
    float sum = e;
#pragma unroll
    for (int o = 32; o > 0; o >>= 1) sum += __shfl_xor(sum, o);
    if (t < 128 && (t & 63) == 0) red2[t >> 6] = sum;
    __syncthreads();
    sum = red2[0] + red2[1];

    if (t < 128) {
        const int ks = t >> 5, quad = (t >> 3) & 3, j = t & 7;
        att2[(size_t)(((ks * 4 + quad) * 128) + n) * 8 + j] = bf16_rn(e / sum);
    }
}

// ---------------------------------------------------------------------------
// K3: out[n, s*128+r] = sum_n' attn[n,n'] * v_s[n',r]. grid 1024 x 256.
// LDS: vT only (~35KB). Wv from pre-split Wsp (p=2), attn from att2.
// ---------------------------------------------------------------------------
__global__ __launch_bounds__(256, 2) void k_out(const float* __restrict__ x,
                                                const unsigned short* __restrict__ Wsp,
                                                const float* __restrict__ b,
                                                const unsigned short* __restrict__ att2,
                                                const float* __restrict__ peT,
                                                float* __restrict__ out) {
    __shared__ unsigned short vT[128 * 136];     // [r][n'] bf16
    __shared__ float bv[128];

    const int t    = threadIdx.x;
    const int lane = t & 63;
    const int wv   = t >> 6;
    const int lid  = lane & 15;
    const int quad = lane >> 4;
    const int s    = blockIdx.x;
    const float ps = peT[s];

    if (t < 128) bv[t] = b[3 * t + 2];
    __syncthreads();

    const f32x4 fzero = {0.f, 0.f, 0.f, 0.f};

    // ---- held xs A-frags: rows n=(wv*2+mt)*16+lid ----
    bf16x8 xh[2][4], xl[2][4];
#pragma unroll
    for (int mt = 0; mt < 2; ++mt) {
        const int row = (wv * 2 + mt) * 16 + lid;
        const float* xp = x + (size_t)row * SD_ + (size_t)s * D_;
#pragma unroll
        for (int ks = 0; ks < 4; ++ks)
            load_split8(xp + ks * 32 + quad * 8, ps, xh[mt][ks], xl[mt][ks]);
    }

    // ---- v-proj: v = xs @ Wv^T (3-term split); vT chunks disjoint, no syncs ----
    for (int rc = 0; rc < 4; ++rc) {
        f32x4 vacc[2][2];
        vacc[0][0] = fzero; vacc[0][1] = fzero; vacc[1][0] = fzero; vacc[1][1] = fzero;
#pragma unroll
        for (int ks = 0; ks < 4; ++ks) {
            const unsigned short* wb =
                Wsp + (size_t)(((2 * 4 + rc) * 4 + ks) * 4 + quad) * 256;
            bf16x8 wh[2], wl[2];
#pragma unroll
            for (int nt = 0; nt < 2; ++nt) {
                wh[nt] = *(const bf16x8*)(wb + (nt * 16 + lid) * 8);
                wl[nt] = *(const bf16x8*)(wb + WSP_PLANE + (nt * 16 + lid) * 8);
            }
#pragma unroll
            for (int mt = 0; mt < 2; ++mt)
#pragma unroll
                for (int nt = 0; nt < 2; ++nt) {
                    vacc[mt][nt] = MFMA16(xh[mt][ks], wh[nt], vacc[mt][nt], 0, 0, 0);
                    vacc[mt][nt] = MFMA16(xh[mt][ks], wl[nt], vacc[mt][nt], 0, 0, 0);
                    vacc[mt][nt] = MFMA16(xl[mt][ks], wh[nt], vacc[mt][nt], 0, 0, 0);
                }
        }
#pragma unroll
        for (int mt = 0; mt < 2; ++mt)
#pragma unroll
            for (int nt = 0; nt < 2; ++nt) {
                const int r = rc * 32 + nt * 16 + lid;
                const float bias = bv[r];
                unsigned short hh[4];
#pragma unroll
                for (int i = 0; i < 4; ++i) hh[i] = bf16_rn(vacc[mt][nt][i] + bias);
                bf16x4 hv = {(short)hh[0], (short)hh[1], (short)hh[2], (short)hh[3]};
                *(bf16x4*)&vT[r * 136 + (wv * 2 + mt) * 16 + quad * 4] = hv;
            }
    }
    __syncthreads();

    // ---- PV: outT = vT @ attnT (plain bf16, attn B-frags from att2) ----
    {
        f32x4 oacc[2][8];
#pragma unroll
        for (int i = 0; i < 2; ++i)
#pragma unroll
            for (int j = 0; j < 8; ++j) oacc[i][j] = fzero;
#pragma unroll
        for (int ks = 0; ks < 4; ++ks) {
            const int kofs = ks * 32 + quad * 8;
            bf16x8 a[2];
#pragma unroll
            for (int mt = 0; mt < 2; ++mt)
                a[mt] = *(const bf16x8*)&vT[((wv * 2 + mt) * 16 + lid) * 136 + kofs];
#pragma unroll
            for (int nt = 0; nt < 8; ++nt) {
                bf16x8 bb = *(const bf16x8*)&att2[(size_t)(((ks * 4 + quad) * 128) +
                                                           (nt * 16 + lid)) * 8];
#pragma unroll
                for (int mt = 0; mt < 2; ++mt)
                    oacc[mt][nt] = MFMA16(a[mt], bb, oacc[mt][nt], 0, 0, 0);
            }
        }
#pragma unroll
        for (int mt = 0; mt < 2; ++mt)
#pragma unroll
            for (int nt = 0; nt < 8; ++nt) {
                const int r = (wv * 2 + mt) * 16 + quad * 4;
                const int n = nt * 16 + lid;
                *(float4*)&out[(size_t)n * SD_ + (size_t)s * D_ + r] = *(float4*)&oacc[mt][nt];
            }
    }
}

// ---------------------------------------------------------------------------
extern "C" void kernel_launch(void* const* d_in, const int* in_sizes, int n_in,
                              void* d_out, int out_size, void* d_ws, size_t ws_size,
                              hipStream_t stream) {
    const float* x = (const float*)d_in[0];
    const float* W = (const float*)d_in[1];
    const float* b = (const float*)d_in[2];
    float* out = (float*)d_out;

    const size_t store_bytes = (size_t)GRID_SC * PSTRIDE * sizeof(float);  // ~32.3 MiB
    const size_t rep_bytes   = (size_t)NREP * PSTRIDE * sizeof(float);     // ~4.2 MB
    const size_t tail_bytes  = (size_t)N_ * N_ * sizeof(unsigned short)        // att2
                             + (size_t)2 * WSP_PLANE * sizeof(unsigned short)  // Wsp
                             + (size_t)S_ * sizeof(float)                      // peT
                             + (size_t)2 * MSP_PLANE * sizeof(unsigned short)  // Msp
                             + (size_t)N_ * sizeof(float);                     // u
    const int store_mode = (ws_size >= store_bytes + tail_bytes) ? 1 : 0;
    const size_t sc_bytes = store_mode ? store_bytes : rep_bytes;

    // ws layout: scores region | att2 | Wsp | peT | Msp | u
    float* scores        = (float*)d_ws;
    unsigned short* att2 = (unsigned short*)((char*)d_ws + sc_bytes);
    unsigned short* Wsp  = att2 + N_ * N_;
    float* peT           = (float*)(Wsp + 2 * WSP_PLANE);
    unsigned short* Msp  = (unsigned short*)(peT + S_);
    float* uvec          = (float*)(Msp + 2 * MSP_PLANE);

    if (!store_mode)
        hipMemsetAsync(scores, 0, sc_bytes, stream);

    hipLaunchKernelGGL(k_prep,    dim3(192),     dim3(256),  0, stream, W, Wsp, peT);
    hipLaunchKernelGGL(k_prepM,   dim3(128),     dim3(128),  0, stream, W, b, Msp, uvec);
    hipLaunchKernelGGL(k_scores,  dim3(GRID_SC), dim3(512),  0, stream, x, Msp, uvec, peT,
                       scores, store_mode);
    hipLaunchKernelGGL(k_softmax, dim3(N_),      dim3(1024), 0, stream, scores,
                       store_mode ? GRID_SC : NREP, att2);
    hipLaunchKernelGGL(k_out,     dim3(1024),    dim3(256),  0, stream, x, Wsp, b, att2,
                       peT, out);
}

// Round 10
// 208.256 us; speedup vs baseline: 1.9199x; 1.3328x over previous
//
#include <hip/hip_runtime.h>
#include <math.h>

#define N_   128
#define S_   1024
#define D_   128
#define SD_  (S_ * D_)     // 131072

#define WSP_PLANE 49152    // 3*4*4*4*32*8  (one hi or lo W plane, elements)
#define NREP 16            // fallback (atomic) replica count
#define SB   2             // s-values per k_scores block
#define GRID_SC (S_ / SB)  // 512
#define QKP  36            // qk row pitch in shorts (72 B = 18 banks: conflict-free
                           // for lid-strided access; 40 was 20 banks -> 2-way)

typedef __attribute__((ext_vector_type(8))) short bf16x8;
typedef __attribute__((ext_vector_type(4))) short bf16x4;
typedef __attribute__((ext_vector_type(4))) float f32x4;
#define MFMA16 __builtin_amdgcn_mfma_f32_16x16x32_bf16

// pe(s): row i = s>>5, col c = s&31; arg = pi*i*1000^(-(c&~1)/128); sin if c even
__device__ __forceinline__ float pe_scale(int s) {
    int i = s >> 5;
    int c = s & 31;
    double rexp = pow(1000.0, -(double)(c & ~1) / 128.0);
    double arg = M_PI * (double)i * rexp;
    return (float)((c & 1) ? cos(arg) : sin(arg));
}

__device__ __forceinline__ unsigned short bf16_rn(float f) {
    unsigned int u = __float_as_uint(f);
    u += 0x7fff + ((u >> 16) & 1);
    return (unsigned short)(u >> 16);
}
__device__ __forceinline__ float bf16_f(unsigned short h) {
    return __uint_as_float(((unsigned int)h) << 16);
}
__device__ __forceinline__ void split2(float f, unsigned short& h, unsigned short& l) {
    h = bf16_rn(f);
    l = bf16_rn(f - bf16_f(h));
}

// load 8 consecutive fp32, scale, split into hi/lo bf16x8 frags
__device__ __forceinline__ void load_split8(const float* p, float scale,
                                            bf16x8& hi, bf16x8& lo) {
    float4 u0 = *(const float4*)(p);
    float4 u1 = *(const float4*)(p + 4);
    unsigned short h[8], l[8];
    split2(u0.x * scale, h[0], l[0]); split2(u0.y * scale, h[1], l[1]);
    split2(u0.z * scale, h[2], l[2]); split2(u0.w * scale, h[3], l[3]);
    split2(u1.x * scale, h[4], l[4]); split2(u1.y * scale, h[5], l[5]);
    split2(u1.z * scale, h[6], l[6]); split2(u1.w * scale, h[7], l[7]);
    hi = bf16x8{(short)h[0],(short)h[1],(short)h[2],(short)h[3],
                (short)h[4],(short)h[5],(short)h[6],(short)h[7]};
    lo = bf16x8{(short)l[0],(short)l[1],(short)l[2],(short)l[3],
                (short)l[4],(short)l[5],(short)l[6],(short)l[7]};
}

// ---------------------------------------------------------------------------
// K0: split W (fp32 [384][128]) into hi/lo bf16 planes in MFMA-frag-swizzled
// layout Wsp[h][p][rc][ks][quad][m(32)][j(8)]. Also fills pe table (1024 f32).
// grid 192 x 256.
// ---------------------------------------------------------------------------
__global__ __launch_bounds__(256) void k_prep(const float* __restrict__ W,
                                              unsigned short* __restrict__ Wsp,
                                              float* __restrict__ peT) {
    const int idx = blockIdx.x * 256 + threadIdx.x;  // 0..49151
    if (idx < S_) peT[idx] = pe_scale(idx);
    const int rg = idx >> 7;         // W row (feature f)
    const int d  = idx & 127;
    const int p  = rg % 3;
    const int r  = rg / 3;
    const int rc = r >> 5, m = r & 31;
    const int ks = d >> 5, quad = (d >> 3) & 3, j = d & 7;
    unsigned short h, l;
    split2(W[idx], h, l);
    const size_t off = (size_t)((((p * 4 + rc) * 4 + ks) * 4 + quad) * 32 + m) * 8 + j;
    Wsp[off] = h;
    Wsp[off + WSP_PLANE] = l;
}

// ---------------------------------------------------------------------------
// K1: per-block partial scores over SB s-values via split-bf16 MFMA.
// REVERT of the M-restructure (R6-R9: structural scratch spill at any launch
// bound) to the R3 two-projection structure, PLUS the one salvageable piece:
// ping-pong qk buffers -> ONE barrier per rc (8/block instead of 16), row
// pitch 36 shorts (18-bank stride, conflict-free) so 2 buffers still allow
// 2 blocks/CU (LDS 75.3 KB). grid GRID_SC x 256.
// store_mode=1: write private 128x128 partial (no atomics, reduced in K2).
// ---------------------------------------------------------------------------
__global__ __launch_bounds__(256, 2) void k_scores(const float* __restrict__ x,
                                                   const unsigned short* __restrict__ Wsp,
                                                   const float* __restrict__ b,
                                                   const float* __restrict__ peT,
                                                   float* __restrict__ sc,
                                                   int store_mode) {
    __shared__ unsigned short qk[2][4][128 * QKP]; // [buf][qh,ql,kh,kl] : [n][r]
    __shared__ float bl[384];

    const int t    = threadIdx.x;
    const int lane = t & 63;
    const int wv   = t >> 6;        // wave 0..3
    const int lid  = lane & 15;
    const int quad = lane >> 4;

    if (t < 128) { bl[t] = b[t]; bl[t + 128] = b[t + 128]; bl[t + 256] = b[t + 256]; }
    __syncthreads();

    const f32x4 fzero = {0.f, 0.f, 0.f, 0.f};
    f32x4 sacc[2][8];
#pragma unroll
    for (int i = 0; i < 2; ++i)
#pragma unroll
        for (int j = 0; j < 8; ++j) sacc[i][j] = fzero;

    for (int ss = 0; ss < SB; ++ss) {
        const int s = blockIdx.x * SB + ss;
        const float ps = peT[s];

        // ---- held xs B-frags: rows n=(wv*2+nt)*16+lid, k=ks*32+quad*8 ----
        bf16x8 xh[2][4], xl[2][4];
#pragma unroll
        for (int nt = 0; nt < 2; ++nt) {
            const int row = (wv * 2 + nt) * 16 + lid;
            const float* xp = x + (size_t)row * SD_ + (size_t)s * D_;
#pragma unroll
            for (int ks = 0; ks < 4; ++ks)
                load_split8(xp + ks * 32 + quad * 8, ps, xh[nt][ks], xl[nt][ks]);
        }

        for (int rc = 0; rc < 4; ++rc) {
            const int buf = rc & 1;   // ping-pong (rc parity; 4 per ss keeps it even)
            // ---- projection: qT = Wp @ xs^T (3-term split), p=0:q 1:k ----
            for (int p = 0; p < 2; ++p) {
                f32x4 pacc[2][2];
                pacc[0][0] = fzero; pacc[0][1] = fzero;
                pacc[1][0] = fzero; pacc[1][1] = fzero;
#pragma unroll
                for (int ks = 0; ks < 4; ++ks) {
                    const unsigned short* wb =
                        Wsp + (size_t)(((p * 4 + rc) * 4 + ks) * 4 + quad) * 256;
                    bf16x8 wh[2], wl[2];
#pragma unroll
                    for (int mt = 0; mt < 2; ++mt) {
                        wh[mt] = *(const bf16x8*)(wb + (mt * 16 + lid) * 8);
                        wl[mt] = *(const bf16x8*)(wb + WSP_PLANE + (mt * 16 + lid) * 8);
                    }
#pragma unroll
                    for (int mt = 0; mt < 2; ++mt)
#pragma unroll
                        for (int nt = 0; nt < 2; ++nt) {
                            pacc[mt][nt] = MFMA16(wh[mt], xh[nt][ks], pacc[mt][nt], 0, 0, 0);
                            pacc[mt][nt] = MFMA16(wh[mt], xl[nt][ks], pacc[mt][nt], 0, 0, 0);
                            pacc[mt][nt] = MFMA16(wl[mt], xh[nt][ks], pacc[mt][nt], 0, 0, 0);
                        }
                }
                // epilogue: +bias, split, write transposed into qk[buf][..][n][r]
#pragma unroll
                for (int mt = 0; mt < 2; ++mt)
#pragma unroll
                    for (int nt = 0; nt < 2; ++nt) {
                        const int n = (wv * 2 + nt) * 16 + lid;
                        unsigned short hh[4], ll[4];
#pragma unroll
                        for (int r = 0; r < 4; ++r) {
                            const int rg = rc * 32 + mt * 16 + quad * 4 + r;
                            float qv = pacc[mt][nt][r] + bl[3 * rg + p];
                            split2(qv, hh[r], ll[r]);
                        }
                        bf16x4 hv = {(short)hh[0], (short)hh[1], (short)hh[2], (short)hh[3]};
                        bf16x4 lv = {(short)ll[0], (short)ll[1], (short)ll[2], (short)ll[3]};
                        *(bf16x4*)&qk[buf][p * 2 + 0][n * QKP + mt * 16 + quad * 4] = hv;
                        *(bf16x4*)&qk[buf][p * 2 + 1][n * QKP + mt * 16 + quad * 4] = lv;
                    }
            }
            __syncthreads();
            // ---- scores += q @ k^T over this 32-r chunk (3-term split) ----
            {
                bf16x8 qh[2], ql[2];
#pragma unroll
                for (int mt = 0; mt < 2; ++mt) {
                    const int row = wv * 32 + mt * 16 + lid;
                    qh[mt] = *(const bf16x8*)&qk[buf][0][row * QKP + quad * 8];
                    ql[mt] = *(const bf16x8*)&qk[buf][1][row * QKP + quad * 8];
                }
#pragma unroll
                for (int ntp = 0; ntp < 8; ++ntp) {
                    const int row = ntp * 16 + lid;
                    bf16x8 kh = *(const bf16x8*)&qk[buf][2][row * QKP + quad * 8];
                    bf16x8 kl = *(const bf16x8*)&qk[buf][3][row * QKP + quad * 8];
#pragma unroll
                    for (int mt = 0; mt < 2; ++mt) {
                        sacc[mt][ntp] = MFMA16(qh[mt], kh, sacc[mt][ntp], 0, 0, 0);
                        sacc[mt][ntp] = MFMA16(qh[mt], kl, sacc[mt][ntp], 0, 0, 0);
                        sacc[mt][ntp] = MFMA16(ql[mt], kh, sacc[mt][ntp], 0, 0, 0);
                    }
                }
            }
            // no trailing barrier: next rc writes the OTHER buffer; reuse of
            // this buffer (rc+2) is ordered by the rc+1 barrier, which every
            // wave passes only after finishing this score phase.
        }
    }

    // ---- write partial (store mode) or atomic accumulate (fallback) ----
    float* rep = sc + (store_mode ? (size_t)blockIdx.x * (N_ * N_)
                                  : (size_t)(blockIdx.x & (NREP - 1)) * (N_ * N_));
#pragma unroll
    for (int mt = 0; mt < 2; ++mt)
#pragma unroll
        for (int ntp = 0; ntp < 8; ++ntp)
#pragma unroll
            for (int r = 0; r < 4; ++r) {
                const int n  = wv * 32 + mt * 16 + quad * 4 + r;
                const int np = ntp * 16 + lid;
                if (store_mode) rep[n * N_ + np] = sacc[mt][ntp][r];
                else            atomicAdd(&rep[n * N_ + np], sacc[mt][ntp][r]);
            }
}

// ---------------------------------------------------------------------------
// K2: sum R partials/replicas, softmax, write attn pre-swizzled into B-frag
// layout att2[ks][quad][n][j]. grid 128 x 1024 threads (32-way replica split).
// ---------------------------------------------------------------------------
__global__ __launch_bounds__(1024) void k_softmax(const float* __restrict__ sc, int R,
                                                  unsigned short* __restrict__ att2) {
    const int n  = blockIdx.x;
    const int t  = threadIdx.x;          // 0..1023
    const int rg = t >> 5;               // 0..31: rep-group
    const int c4 = (t & 31) * 4;         // column quad

    float4 a = {0.f, 0.f, 0.f, 0.f};
    for (int rep = rg; rep < R; rep += 32) {
        const float4 p = *(const float4*)&sc[(size_t)rep * (N_ * N_) + n * N_ + c4];
        a.x += p.x; a.y += p.y; a.z += p.z; a.w += p.w;
    }
    __shared__ float tmp[32][128];
    *(float4*)&tmp[rg][c4] = a;
    __syncthreads();

    __shared__ float red[2];
    __shared__ float red2[2];

    float v = 0.f;
    if (t < 128) {
#pragma unroll
        for (int g = 0; g < 32; ++g) v += tmp[g][t];
        v *= 0.08838834764831845f;   // 1/sqrt(128)
    }

    float m = v;
#pragma unroll
    for (int o = 32; o > 0; o >>= 1) m = fmaxf(m, __shfl_xor(m, o));
    if (t < 128 && (t & 63) == 0) red[t >> 6] = m;
    __syncthreads();
    m = fmaxf(red[0], red[1]);

    float e = (t < 128) ? expf(v - m) : 0.f;
    float sum = e;
#pragma unroll
    for (int o = 32; o > 0; o >>= 1) sum += __shfl_xor(sum, o);
    if (t < 128 && (t & 63) == 0) red2[t >> 6] = sum;
    __syncthreads();
    sum = red2[0] + red2[1];

    if (t < 128) {
        const int ks = t >> 5, quad = (t >> 3) & 3, j = t & 7;
        att2[(size_t)(((ks * 4 + quad) * 128) + n) * 8 + j] = bf16_rn(e / sum);
    }
}

// ---------------------------------------------------------------------------
// K3: out[n, s*128+r] = sum_n' attn[n,n'] * v_s[n',r]. grid 1024 x 256.
// LDS: vT only (~35KB). Wv from pre-split Wsp (p=2), attn from att2.
// ---------------------------------------------------------------------------
__global__ __launch_bounds__(256, 2) void k_out(const float* __restrict__ x,
                                                const unsigned short* __restrict__ Wsp,
                                                const float* __restrict__ b,
                                                const unsigned short* __restrict__ att2,
                                                const float* __restrict__ peT,
                                                float* __restrict__ out) {
    __shared__ unsigned short vT[128 * 136];     // [r][n'] bf16
    __shared__ float bv[128];

    const int t    = threadIdx.x;
    const int lane = t & 63;
    const int wv   = t >> 6;
    const int lid  = lane & 15;
    const int quad = lane >> 4;
    const int s    = blockIdx.x;
    const float ps = peT[s];

    if (t < 128) bv[t] = b[3 * t + 2];
    __syncthreads();

    const f32x4 fzero = {0.f, 0.f, 0.f, 0.f};

    // ---- held xs A-frags: rows n=(wv*2+mt)*16+lid ----
    bf16x8 xh[2][4], xl[2][4];
#pragma unroll
    for (int mt = 0; mt < 2; ++mt) {
        const int row = (wv * 2 + mt) * 16 + lid;
        const float* xp = x + (size_t)row * SD_ + (size_t)s * D_;
#pragma unroll
        for (int ks = 0; ks < 4; ++ks)
            load_split8(xp + ks * 32 + quad * 8, ps, xh[mt][ks], xl[mt][ks]);
    }

    // ---- v-proj: v = xs @ Wv^T (3-term split); vT chunks disjoint, no syncs ----
    for (int rc = 0; rc < 4; ++rc) {
        f32x4 vacc[2][2];
        vacc[0][0] = fzero; vacc[0][1] = fzero; vacc[1][0] = fzero; vacc[1][1] = fzero;
#pragma unroll
        for (int ks = 0; ks < 4; ++ks) {
            const unsigned short* wb =
                Wsp + (size_t)(((2 * 4 + rc) * 4 + ks) * 4 + quad) * 256;
            bf16x8 wh[2], wl[2];
#pragma unroll
            for (int nt = 0; nt < 2; ++nt) {
                wh[nt] = *(const bf16x8*)(wb + (nt * 16 + lid) * 8);
                wl[nt] = *(const bf16x8*)(wb + WSP_PLANE + (nt * 16 + lid) * 8);
            }
#pragma unroll
            for (int mt = 0; mt < 2; ++mt)
#pragma unroll
                for (int nt = 0; nt < 2; ++nt) {
                    vacc[mt][nt] = MFMA16(xh[mt][ks], wh[nt], vacc[mt][nt], 0, 0, 0);
                    vacc[mt][nt] = MFMA16(xh[mt][ks], wl[nt], vacc[mt][nt], 0, 0, 0);
                    vacc[mt][nt] = MFMA16(xl[mt][ks], wh[nt], vacc[mt][nt], 0, 0, 0);
                }
        }
#pragma unroll
        for (int mt = 0; mt < 2; ++mt)
#pragma unroll
            for (int nt = 0; nt < 2; ++nt) {
                const int r = rc * 32 + nt * 16 + lid;
                const float bias = bv[r];
                unsigned short hh[4];
#pragma unroll
                for (int i = 0; i < 4; ++i) hh[i] = bf16_rn(vacc[mt][nt][i] + bias);
                bf16x4 hv = {(short)hh[0], (short)hh[1], (short)hh[2], (short)hh[3]};
                *(bf16x4*)&vT[r * 136 + (wv * 2 + mt) * 16 + quad * 4] = hv;
            }
    }
    __syncthreads();

    // ---- PV: outT = vT @ attnT (plain bf16, attn B-frags from att2) ----
    {
        f32x4 oacc[2][8];
#pragma unroll
        for (int i = 0; i < 2; ++i)
#pragma unroll
            for (int j = 0; j < 8; ++j) oacc[i][j] = fzero;
#pragma unroll
        for (int ks = 0; ks < 4; ++ks) {
            const int kofs = ks * 32 + quad * 8;
            bf16x8 a[2];
#pragma unroll
            for (int mt = 0; mt < 2; ++mt)
                a[mt] = *(const bf16x8*)&vT[((wv * 2 + mt) * 16 + lid) * 136 + kofs];
#pragma unroll
            for (int nt = 0; nt < 8; ++nt) {
                bf16x8 bb = *(const bf16x8*)&att2[(size_t)(((ks * 4 + quad) * 128) +
                                                           (nt * 16 + lid)) * 8];
#pragma unroll
                for (int mt = 0; mt < 2; ++mt)
                    oacc[mt][nt] = MFMA16(a[mt], bb, oacc[mt][nt], 0, 0, 0);
            }
        }
#pragma unroll
        for (int mt = 0; mt < 2; ++mt)
#pragma unroll
            for (int nt = 0; nt < 8; ++nt) {
                const int r = (wv * 2 + mt) * 16 + quad * 4;
                const int n = nt * 16 + lid;
                *(float4*)&out[(size_t)n * SD_ + (size_t)s * D_ + r] = *(float4*)&oacc[mt][nt];
            }
    }
}

// ---------------------------------------------------------------------------
extern "C" void kernel_launch(void* const* d_in, const int* in_sizes, int n_in,
                              void* d_out, int out_size, void* d_ws, size_t ws_size,
                              hipStream_t stream) {
    const float* x = (const float*)d_in[0];
    const float* W = (const float*)d_in[1];
    const float* b = (const float*)d_in[2];
    float* out = (float*)d_out;

    const size_t store_bytes = (size_t)GRID_SC * N_ * N_ * sizeof(float);  // 32 MB
    const size_t rep_bytes   = (size_t)NREP * N_ * N_ * sizeof(float);     // 1 MB
    const size_t tail_bytes  = (size_t)N_ * N_ * sizeof(unsigned short)        // att2
                             + (size_t)2 * WSP_PLANE * sizeof(unsigned short)  // Wsp
                             + (size_t)S_ * sizeof(float);                     // peT
    const int store_mode = (ws_size >= store_bytes + tail_bytes) ? 1 : 0;
    const size_t sc_bytes = store_mode ? store_bytes : rep_bytes;

    // ws layout: scores region | att2 32 KB | Wsp 192 KB | peT 4 KB
    float* scores        = (float*)d_ws;
    unsigned short* att2 = (unsigned short*)((char*)d_ws + sc_bytes);
    unsigned short* Wsp  = att2 + N_ * N_;
    float* peT           = (float*)(Wsp + 2 * WSP_PLANE);

    if (!store_mode)
        hipMemsetAsync(scores, 0, sc_bytes, stream);

    hipLaunchKernelGGL(k_prep,    dim3(192),     dim3(256),  0, stream, W, Wsp, peT);
    hipLaunchKernelGGL(k_scores,  dim3(GRID_SC), dim3(256),  0, stream, x, Wsp, b, peT,
                       scores, store_mode);
    hipLaunchKernelGGL(k_softmax, dim3(N_),      dim3(1024), 0, stream, scores,
                       store_mode ? GRID_SC : NREP, att2);
    hipLaunchKernelGGL(k_out,     dim3(1024),    dim3(256),  0, stream, x, Wsp, b, att2,
                       peT, out);
}